// Round 19
// baseline (2802.523 us; speedup 1.0000x reference)
//
#include <hip/hip_runtime.h>
#include <cmath>

typedef unsigned short u16;
typedef unsigned int u32;

// Problem constants
constexpr int NB = 16;            // batch
constexpr int NT = 2048;          // seq len
constexpr int ND = 512;           // embed dim
constexpr int NL = 6;             // layers
constexpr int NH = 1024;          // mlp hidden
constexpr int NK = 256;           // freq bands kept
constexpr int NM = NB * NT;       // 32768 rows

constexpr float PI2 = 6.283185307179586f;

typedef short bf16x8 __attribute__((ext_vector_type(8)));
typedef float f32x4 __attribute__((ext_vector_type(4)));

__device__ __forceinline__ float gelu_exact(float v) {
    return 0.5f * v * (1.0f + erff(v * 0.70710678118654752f));
}

__device__ __forceinline__ u16 f2bf(float f) {
    union { float f; u32 u; } v; v.f = f;
    u32 r = v.u + 0x7FFFu + ((v.u >> 16) & 1u);
    return (u16)(r >> 16);
}

__device__ __forceinline__ float bf2f(u16 h) {
    union { u32 u; float f; } v; v.u = ((u32)h) << 16;
    return v.f;
}

__device__ __forceinline__ float block_sum256(float val, float* lds4) {
#pragma unroll
    for (int o = 32; o > 0; o >>= 1) val += __shfl_down(val, o);
    int lane = threadIdx.x & 63, wid = threadIdx.x >> 6;
    if (lane == 0) lds4[wid] = val;
    __syncthreads();
    float t = lds4[0] + lds4[1] + lds4[2] + lds4[3];
    __syncthreads();
    return t;
}

// XCD-chunked block swizzle (R12-proven). Tile size passed in.
__device__ __forceinline__ void swz_block_t(int bm, int& row0, int& col0) {
    int nwg = gridDim.x * gridDim.y;
    int wg = blockIdx.x + blockIdx.y * gridDim.x;
    int L = wg;
    if ((nwg & 7) == 0) {
        int q = nwg >> 3;
        L = (wg & 7) * q + (wg >> 3);
    }
    int ncol = gridDim.y;
    row0 = (L / ncol) * bm;
    col0 = (L % ncol) * 128;
}

// ---------------- twiddle table: entry (h-1)+k = exp(-i*pi*k/h) --------------
__global__ void twiddle_kernel(float2* __restrict__ tw) {
    int idx = blockIdx.x * 256 + threadIdx.x;
    if (idx < 2047) {
        u32 v = idx + 1;
        u32 h = 1u << (31 - __clz(v));
        u32 k = v - h;
        float a = -(float)M_PI * (float)k / (float)h;
        tw[idx] = make_float2(cosf(a), sinf(a));
    }
}

// ---------------- K1: direct DFT of byte signal, 16x256 bins -----------------
__global__ void dft_kernel(const int* __restrict__ bytes, const float* __restrict__ fb,
                           float* __restrict__ mag, float* __restrict__ cph,
                           float* __restrict__ sph) {
    __shared__ float lr[4], li[4];
    int b = blockIdx.x, f = blockIdx.y;
    float re = 0.f, im = 0.f;
    for (int t = threadIdx.x; t < NT; t += 256) {
        float s = (float)bytes[b * NT + t] * (1.0f / 127.5f) - 1.0f;
        int idx = (t * f) & (NT - 1);
        float a = (float)idx * (PI2 / NT);
        float sn, cs;
        sincosf(a, &sn, &cs);
        re += s * cs;
        im -= s * sn;
    }
#pragma unroll
    for (int o = 32; o > 0; o >>= 1) {
        re += __shfl_down(re, o);
        im += __shfl_down(im, o);
    }
    int lane = threadIdx.x & 63, wid = threadIdx.x >> 6;
    if (lane == 0) { lr[wid] = re; li[wid] = im; }
    __syncthreads();
    if (threadIdx.x == 0) {
        float R = lr[0] + lr[1] + lr[2] + lr[3];
        float I = li[0] + li[1] + li[2] + li[3];
        float m = sqrtf(R * R + I * I);
        mag[b * NK + f] = m * fb[f];
        float inv = (m > 0.f) ? 1.0f / m : 0.f;
        cph[b * NK + f] = (m > 0.f) ? R * inv : 1.0f;  // cos(angle)
        sph[b * NK + f] = I * inv;                     // sin(angle)
    }
}

// -------- K2: spectral features [mag | sin(phase)] -> split bf16 hi/lo -------
__global__ void feats_split_kernel(const float* __restrict__ mag,
                                   const float* __restrict__ cph,
                                   const float* __restrict__ sph,
                                   u16* __restrict__ hi, u16* __restrict__ lo) {
    int idx = blockIdx.x * 256 + threadIdx.x;
    int d = idx & (ND - 1);
    int m = idx >> 9;
    int b = m >> 11, t = m & (NT - 1);
    float v;
    if (d < NK) {
        v = mag[b * NK + d];
    } else {
        int f = d - NK;
        int a = (t * f) & (NT - 1);
        float sn, cs;
        sincosf((float)a * (PI2 / NT), &sn, &cs);
        v = sph[b * NK + f] * cs + cph[b * NK + f] * sn;  // sin(bp + theta)
    }
    u16 h = f2bf(v);
    hi[idx] = h;
    lo[idx] = f2bf(v - bf2f(h));
}

// ------- LayerNorm: OBF 0=f32 out, 1=bf16 out, 2=split hi/lo pair out --------
template <int NV, int GELU, int OBF>
__global__ void ln_kernel(const float* __restrict__ in, const float* __restrict__ g,
                          const float* __restrict__ bta, void* __restrict__ outv) {
    __shared__ float lds4[4];
    constexpr int NE = NV / 256;
    size_t row = blockIdx.x;
    const float* p = in + row * NV;
    float v[NE];
    float sum = 0.f;
#pragma unroll
    for (int i = 0; i < NE; ++i) {
        v[i] = p[threadIdx.x + 256 * i];
        sum += v[i];
    }
    sum = block_sum256(sum, lds4);
    float mean = sum * (1.0f / NV);
    float sq = 0.f;
#pragma unroll
    for (int i = 0; i < NE; ++i) {
        float d = v[i] - mean;
        sq += d * d;
    }
    sq = block_sum256(sq, lds4);
    float inv = rsqrtf(sq * (1.0f / NV) + 1e-5f);
#pragma unroll
    for (int i = 0; i < NE; ++i) {
        int c = threadIdx.x + 256 * i;
        float r = (v[i] - mean) * inv * g[c] + bta[c];
        if (GELU) r = gelu_exact(r);
        if (OBF == 2) {
            u16* o = (u16*)outv + row * (2 * NV);
            u16 hb = f2bf(r);
            o[c] = hb;
            o[NV + c] = f2bf(r - bf2f(hb));
        } else if (OBF == 1) {
            ((u16*)outv)[row * NV + c] = f2bf(r);
        } else {
            ((float*)outv)[row * NV + c] = r;
        }
    }
}

// ------- fused LN + 512-pt FFT along D, WAVE-PER-ROW (4 rows/block) ----------
__global__ void ln_fftd_kernel(const float* __restrict__ x, const float* __restrict__ g,
                               const float* __restrict__ bta, float* __restrict__ P,
                               const float2* __restrict__ twid) {
    __shared__ float sr[4][512], si[4][512];  // 16 KiB
    int wv = threadIdx.x >> 6, lane = threadIdx.x & 63;
    int rlocal = blockIdx.x * 4 + wv;
    const float* p = x + (size_t)rlocal * ND;
    float v[8];
    float s = 0.f;
#pragma unroll
    for (int j = 0; j < 8; ++j) { v[j] = p[lane + 64 * j]; s += v[j]; }
#pragma unroll
    for (int o = 32; o > 0; o >>= 1) s += __shfl_down(s, o);
    s = __shfl(s, 0);
    float mean = s * (1.0f / ND);
    float q = 0.f;
#pragma unroll
    for (int j = 0; j < 8; ++j) { float d = v[j] - mean; q += d * d; }
#pragma unroll
    for (int o = 32; o > 0; o >>= 1) q += __shfl_down(q, o);
    q = __shfl(q, 0);
    float inv = rsqrtf(q * (1.0f / ND) + 1e-5f);
#pragma unroll
    for (int j = 0; j < 8; ++j) {
        int i = lane + 64 * j;
        int r = __brev((unsigned)i) >> 23;  // 9-bit reverse
        sr[wv][r] = (v[j] - mean) * inv * g[i] + bta[i];
        si[wv][r] = 0.f;
    }
    for (int len = 2; len <= 512; len <<= 1) {
        int half = len >> 1;
#pragma unroll
        for (int qq = lane; qq < 256; qq += 64) {
            int k = qq & (half - 1);
            int j = ((qq - k) << 1) + k;
            float2 tw = twid[(half - 1) + k];
            float cs = tw.x, sn = tw.y;
            float ur = sr[wv][j], ui = si[wv][j];
            float vr = sr[wv][j + half], vi = si[wv][j + half];
            float tr = vr * cs - vi * sn;
            float ti = vr * sn + vi * cs;
            sr[wv][j] = ur + tr;
            si[wv][j] = ui + ti;
            sr[wv][j + half] = ur - tr;
            si[wv][j + half] = ui - ti;
        }
    }
    float* out = P + (size_t)rlocal * ND;
#pragma unroll
    for (int j = 0; j < 8; ++j) {
        int i = lane + 64 * j;
        out[i] = (i <= 256) ? sr[wv][i] : si[wv][i - 256];
    }
}

// ---------------- tiled transpose: PT[b][idx][t] = P[b*T+t][idx] -------------
__global__ void transpose_bt_kernel(const float* __restrict__ P, float* __restrict__ PT) {
    __shared__ float tile[32][33];
    int b = blockIdx.z, t0 = blockIdx.x * 32, d0 = blockIdx.y * 32;
    int j = threadIdx.x & 31, i0 = threadIdx.x >> 5;
    for (int i = i0; i < 32; i += 8)
        tile[i][j] = P[((size_t)(b * NT + t0 + i)) * ND + d0 + j];
    __syncthreads();
    for (int i = i0; i < 32; i += 8)
        PT[((size_t)(b * ND + d0 + i)) * NT + t0 + j] = tile[j][i];
}

// ---------------- FFT along T (2048-pt per column d=0..256) ------------------
__global__ void fft_t2048_kernel(const float* __restrict__ PT, float* __restrict__ Mt,
                                 const float2* __restrict__ twid) {
    __shared__ float sr[2048], si[2048];  // 16 KiB
    int b = blockIdx.x;
    int d = blockIdx.y;  // 0..256
    const float* zr = PT + ((size_t)(b * ND + d)) * NT;
    const float* zi = PT + ((size_t)(b * ND + 256 + d)) * NT;  // valid for 1<=d<=255
    bool has_im = (d != 0) && (d != 256);
    for (int t = threadIdx.x; t < 2048; t += 256) {
        int r = __brev((unsigned)t) >> 21;  // 11-bit reverse
        sr[r] = zr[t];
        si[r] = has_im ? zi[t] : 0.f;
    }
    __syncthreads();
    for (int len = 2; len <= 2048; len <<= 1) {
        int half = len >> 1;
        for (int q = threadIdx.x; q < 1024; q += 256) {
            int k = q & (half - 1);
            int j = ((q - k) << 1) + k;
            float2 tw = twid[(half - 1) + k];
            float cs = tw.x, sn = tw.y;
            float ur = sr[j], ui = si[j];
            float vr = sr[j + half], vi = si[j + half];
            float tr = vr * cs - vi * sn;
            float ti = vr * sn + vi * cs;
            sr[j] = ur + tr;
            si[j] = ui + ti;
            sr[j + half] = ur - tr;
            si[j + half] = ui - ti;
        }
        __syncthreads();
    }
    float* m0 = Mt + ((size_t)(b * ND + d)) * NT;
    for (int t = threadIdx.x; t < 2048; t += 256) m0[t] = sr[t];
    if (has_im) {
        float* m1 = Mt + ((size_t)(b * ND + (512 - d))) * NT;
        for (int t = threadIdx.x; t < 2048; t += 256) m1[t] = sr[(2048 - t) & 2047];
    }
}

// ------- FUSED: x[b,t,d] += Mt[b,d,t]; then LN2 -> ybf (bf16) ---------------
__global__ void addt_ln_kernel(const float* __restrict__ Mt, float* __restrict__ x,
                               const float* __restrict__ g, const float* __restrict__ bta,
                               u16* __restrict__ yb) {
    __shared__ float tile[512 * 17];  // [d][tloc] stride 17 (34.8KB, 2-way banks)
    int b = blockIdx.y, t0 = blockIdx.x * 16;
    int tid = threadIdx.x;
    for (int lin = tid; lin < 512 * 16; lin += 256) {
        int tloc = lin & 15, d = lin >> 4;
        tile[d * 17 + tloc] = Mt[((size_t)(b * ND + d)) * NT + t0 + tloc];
    }
    __syncthreads();
    int lane = tid & 63, wv = tid >> 6;
#pragma unroll
    for (int rr = 0; rr < 4; ++rr) {
        int tloc = wv * 4 + rr;
        size_t row = (size_t)(b * NT + t0 + tloc);
        float v[8];
        float s = 0.f;
#pragma unroll
        for (int e = 0; e < 8; ++e) {
            int d = lane + 64 * e;
            v[e] = x[row * ND + d] + tile[d * 17 + tloc];
            s += v[e];
        }
#pragma unroll
        for (int o = 32; o > 0; o >>= 1) s += __shfl_down(s, o);
        s = __shfl(s, 0);
        float mean = s * (1.0f / ND);
        float q = 0.f;
#pragma unroll
        for (int e = 0; e < 8; ++e) { float d2 = v[e] - mean; q += d2 * d2; }
#pragma unroll
        for (int o = 32; o > 0; o >>= 1) q += __shfl_down(q, o);
        q = __shfl(q, 0);
        float inv = rsqrtf(q * (1.0f / ND) + 1e-5f);
#pragma unroll
        for (int e = 0; e < 8; ++e) {
            int d = lane + 64 * e;
            x[row * ND + d] = v[e];
            yb[row * ND + d] = f2bf((v[e] - mean) * inv * g[d] + bta[d]);
        }
    }
}

// ---------------- weight transpose + f32->bf16: Wt[n][k] = W[k][n] -----------
__global__ void wconv_kernel(const float* __restrict__ W, u16* __restrict__ Wt,
                             int K, int N) {
    __shared__ float tile[32][33];
    size_t moff = (size_t)blockIdx.z * K * N;
    int n0 = blockIdx.x * 32, k0 = blockIdx.y * 32;
    int j = threadIdx.x & 31, i0 = threadIdx.x >> 5;
    for (int i = i0; i < 32; i += 8)
        tile[i][j] = W[moff + (size_t)(k0 + i) * N + n0 + j];
    __syncthreads();
    for (int i = i0; i < 32; i += 8)
        Wt[moff + (size_t)(n0 + i) * K + k0 + j] = f2bf(tile[j][i]);
}

// ------- bf16 MFMA GEMM: 256x128 tile, 8 waves, 2-buffer gload_lds -----------
template <int GELU, int ACC, int OBF, int ADDB>
__global__ __launch_bounds__(512) void mfma_gemm(
    const u16* __restrict__ A, int lda, const u16* __restrict__ Wt,
    const float* __restrict__ bias, void* __restrict__ Cv, int Kd, int Nd) {
    __shared__ __align__(16) u16 Al[2][8192];
    __shared__ __align__(16) u16 Bl[2][4096];
    int tid = threadIdx.x;
    int row0, col0;
    swz_block_t(256, row0, col0);
    int lane = tid & 63, w = tid >> 6;
    int wr = w >> 1, wc = w & 1;      // wr 0..3, wc 0..1
    int kg = lane >> 4, ln16 = lane & 15;

    f32x4 acc[4][4] = {};

    auto stage = [&](int buf, int t) {
        int k0 = t << 5;
#pragma unroll
        for (int i = 0; i < 2; ++i) {   // A: 1024 slots, 512 threads
            int s = i * 512 + tid;
            int skg = s >> 8, r = s & 255;
            const u16* ga = A + (size_t)(row0 + r) * lda + k0 + skg * 8;
            __builtin_amdgcn_global_load_lds(
                (const __attribute__((address_space(1))) void*)ga,
                (__attribute__((address_space(3))) void*)&Al[buf][s * 8], 16, 0, 0);
        }
        {                               // B: 512 slots
            int s = tid;
            int skg = s >> 7, r = s & 127;
            const u16* gb = Wt + (size_t)(col0 + r) * Kd + k0 + skg * 8;
            __builtin_amdgcn_global_load_lds(
                (const __attribute__((address_space(1))) void*)gb,
                (__attribute__((address_space(3))) void*)&Bl[buf][s * 8], 16, 0, 0);
        }
    };
    auto compute = [&](int buf) {
        bf16x8 af[4], bfr[4];
#pragma unroll
        for (int mi = 0; mi < 4; ++mi)
            af[mi] = *(const bf16x8*)&Al[buf][(kg * 256 + wr * 64 + mi * 16 + ln16) * 8];
#pragma unroll
        for (int ni = 0; ni < 4; ++ni)
            bfr[ni] = *(const bf16x8*)&Bl[buf][(kg * 128 + wc * 64 + ni * 16 + ln16) * 8];
#pragma unroll
        for (int mi = 0; mi < 4; ++mi)
#pragma unroll
            for (int ni = 0; ni < 4; ++ni)
                acc[mi][ni] = __builtin_amdgcn_mfma_f32_16x16x32_bf16(
                    af[mi], bfr[ni], acc[mi][ni], 0, 0, 0);
    };

    int nt = Kd >> 5;
    stage(0, 0);
    __syncthreads();
    int cur = 0;
    for (int t = 1; t < nt; ++t) {
        stage(cur ^ 1, t);
        compute(cur);
        __syncthreads();
        cur ^= 1;
    }
    compute(cur);

#pragma unroll
    for (int mi = 0; mi < 4; ++mi) {
#pragma unroll
        for (int ni = 0; ni < 4; ++ni) {
            int col = col0 + wc * 64 + ni * 16 + ln16;
            float bv = ADDB ? bias[col] : 0.f;
#pragma unroll
            for (int j = 0; j < 4; ++j) {
                int row = row0 + wr * 64 + mi * 16 + kg * 4 + j;
                float v = acc[mi][ni][j] + bv;
                if (GELU) v = gelu_exact(v);
                size_t o = (size_t)row * Nd + col;
                if (OBF) {
                    ((u16*)Cv)[o] = f2bf(v);
                } else {
                    float* C = (float*)Cv;
                    if (ACC) v += C[o];
                    C[o] = v;
                }
            }
        }
    }
}

// ------- fused split-bf16 GEMM: 256x128 tile, 8 waves, 2-buffer --------------
// C = (Ahi + Alo) @ Wt^T + bias (f32 out). LDS 80KB -> 2 blocks/CU, 16 waves.
__global__ __launch_bounds__(512) void mfma_gemm2(
    const u16* __restrict__ Ahi, const u16* __restrict__ Alo, int lda,
    const u16* __restrict__ Wt, const float* __restrict__ bias,
    float* __restrict__ C, int Kd, int Nd) {
    __shared__ __align__(16) u16 Ah[2][8192];
    __shared__ __align__(16) u16 Al2[2][8192];
    __shared__ __align__(16) u16 Bl[2][4096];
    int tid = threadIdx.x;
    int row0, col0;
    swz_block_t(256, row0, col0);
    int lane = tid & 63, w = tid >> 6;
    int wr = w >> 1, wc = w & 1;
    int kg = lane >> 4, ln16 = lane & 15;

    f32x4 acc[4][4] = {};

    auto stage = [&](int buf, int t) {
        int k0 = t << 5;
#pragma unroll
        for (int i = 0; i < 2; ++i) {   // A_hi/A_lo: 1024 slots each
            int s = i * 512 + tid;
            int skg = s >> 8, r = s & 255;
            size_t aoff = (size_t)(row0 + r) * lda + k0 + skg * 8;
            __builtin_amdgcn_global_load_lds(
                (const __attribute__((address_space(1))) void*)(Ahi + aoff),
                (__attribute__((address_space(3))) void*)&Ah[buf][s * 8], 16, 0, 0);
            __builtin_amdgcn_global_load_lds(
                (const __attribute__((address_space(1))) void*)(Alo + aoff),
                (__attribute__((address_space(3))) void*)&Al2[buf][s * 8], 16, 0, 0);
        }
        {                               // B: 512 slots
            int s = tid;
            int skg = s >> 7, r = s & 127;
            const u16* gb = Wt + (size_t)(col0 + r) * Kd + k0 + skg * 8;
            __builtin_amdgcn_global_load_lds(
                (const __attribute__((address_space(1))) void*)gb,
                (__attribute__((address_space(3))) void*)&Bl[buf][s * 8], 16, 0, 0);
        }
    };
    auto compute = [&](int buf) {
        bf16x8 ah[4], al[4], bfr[4];
#pragma unroll
        for (int mi = 0; mi < 4; ++mi) {
            int sl = (kg * 256 + wr * 64 + mi * 16 + ln16) * 8;
            ah[mi] = *(const bf16x8*)&Ah[buf][sl];
            al[mi] = *(const bf16x8*)&Al2[buf][sl];
        }
#pragma unroll
        for (int ni = 0; ni < 4; ++ni)
            bfr[ni] = *(const bf16x8*)&Bl[buf][(kg * 128 + wc * 64 + ni * 16 + ln16) * 8];
#pragma unroll
        for (int mi = 0; mi < 4; ++mi)
#pragma unroll
            for (int ni = 0; ni < 4; ++ni) {
                acc[mi][ni] = __builtin_amdgcn_mfma_f32_16x16x32_bf16(
                    ah[mi], bfr[ni], acc[mi][ni], 0, 0, 0);
                acc[mi][ni] = __builtin_amdgcn_mfma_f32_16x16x32_bf16(
                    al[mi], bfr[ni], acc[mi][ni], 0, 0, 0);
            }
    };

    int nt = Kd >> 5;
    stage(0, 0);
    __syncthreads();
    int cur = 0;
    for (int t = 1; t < nt; ++t) {
        stage(cur ^ 1, t);
        compute(cur);
        __syncthreads();
        cur ^= 1;
    }
    compute(cur);

#pragma unroll
    for (int mi = 0; mi < 4; ++mi) {
#pragma unroll
        for (int ni = 0; ni < 4; ++ni) {
            int col = col0 + wc * 64 + ni * 16 + ln16;
            float bv = bias[col];
#pragma unroll
            for (int j = 0; j < 4; ++j) {
                int row = row0 + wr * 64 + mi * 16 + kg * 4 + j;
                C[(size_t)row * Nd + col] = acc[mi][ni][j] + bv;
            }
        }
    }
}

extern "C" void kernel_launch(void* const* d_in, const int* in_sizes, int n_in,
                              void* d_out, int out_size, void* d_ws, size_t ws_size,
                              hipStream_t stream) {
    const int* byte_ids     = (const int*)d_in[0];
    const float* freq_bands = (const float*)d_in[1];
    const float* fp_w1   = (const float*)d_in[2];
    const float* fp_b1   = (const float*)d_in[3];
    const float* fp_ln_g = (const float*)d_in[4];
    const float* fp_ln_b = (const float*)d_in[5];
    const float* fp_w2   = (const float*)d_in[6];
    const float* fp_b2   = (const float*)d_in[7];
    const float* blk_ln1_g = (const float*)d_in[8];
    const float* blk_ln1_b = (const float*)d_in[9];
    const float* blk_ln2_g = (const float*)d_in[10];
    const float* blk_ln2_b = (const float*)d_in[11];
    const float* blk_w1  = (const float*)d_in[12];
    const float* blk_b1  = (const float*)d_in[13];
    const float* blk_w2  = (const float*)d_in[14];
    const float* blk_b2  = (const float*)d_in[15];
    const float* norm_g  = (const float*)d_in[16];
    const float* norm_b  = (const float*)d_in[17];
    const float* out_w   = (const float*)d_in[18];
    const float* out_b   = (const float*)d_in[19];
    float* out = (float*)d_out;
    char* base = (char*)d_ws;
    char* obase = (char*)d_out;
    const size_t MB = 1048576;

    // ---- Workspace map (192 MiB, full-batch mixing) — same as R16-R18:
    u16* fhi     = (u16*)base;
    u16* flo     = (u16*)(base + 32 * MB);
    float* xA    = (float*)base;
    float* hfp   = (float*)(base + 64 * MB);
    u16* h2      = (u16*)hfp;
    float* Zbuf  = (float*)(base + 64 * MB);     // [M,512] f32 (64MB)
    float* PTbuf = (float*)(base + 128 * MB);    // [B,512,2048] f32 (64MB)
    float* Mtbuf = Zbuf;
    u16* hmlp    = (u16*)(base + 64 * MB);       // [M,1024] bf16
    u16* ybf     = (u16*)(base + 128 * MB);      // [M,512] bf16
    u16* outwt   = (u16*)(base + 64 * MB);       // [256][512] (written late)
    u16* fpw1t   = (u16*)obase;
    u16* fpw2t   = (u16*)(obase + 1 * MB);
    float* mag   = (float*)(obase + 2 * MB);
    float* cph   = mag + NB * NK;
    float* sph   = cph + NB * NK;
    float2* twid = (float2*)(obase + 4 * MB);
    u16* blkw1t  = (u16*)(obase + 6 * MB);       // 6 x [1024][512]
    u16* blkw2t  = (u16*)(obase + 12 * MB);      // 6 x [512][1024]

    // 0) twiddle table
    twiddle_kernel<<<8, 256, 0, stream>>>(twid);

    // 1) spectral embedding -> split bf16 feats
    dft_kernel<<<dim3(NB, NK), 256, 0, stream>>>(byte_ids, freq_bands, mag, cph, sph);
    feats_split_kernel<<<(NM * ND) / 256, 256, 0, stream>>>(mag, cph, sph, fhi, flo);
    wconv_kernel<<<dim3(NH / 32, ND / 32, 1), 256, 0, stream>>>(fp_w1, fpw1t, ND, NH);
    wconv_kernel<<<dim3(ND / 32, NH / 32, 1), 256, 0, stream>>>(fp_w2, fpw2t, NH, ND);
    wconv_kernel<<<dim3(NH / 32, ND / 32, NL), 256, 0, stream>>>(blk_w1, blkw1t, ND, NH);
    wconv_kernel<<<dim3(ND / 32, NH / 32, NL), 256, 0, stream>>>(blk_w2, blkw2t, NH, ND);

    // 2) freq_proj via fused split-bf16 MFMA (256-tile)
    mfma_gemm2<<<dim3(NM / 256, NH / 128), 512, 0, stream>>>(
        fhi, flo, ND, fpw1t, fp_b1, hfp, ND, NH);
    ln_kernel<NH, 1, 2><<<NM, 256, 0, stream>>>(hfp, fp_ln_g, fp_ln_b, h2);
    mfma_gemm2<<<dim3(NM / 256, ND / 128), 512, 0, stream>>>(
        h2, h2 + NH, 2 * NH, fpw2t, fp_b2, xA, NH, ND);

    // 3) spectral MLP blocks: full-batch mixing (f32) + MLP bf16 MFMA (256-tile)
    for (int l = 0; l < NL; ++l) {
        ln_fftd_kernel<<<NM / 4, 256, 0, stream>>>(
            xA, blk_ln1_g + l * ND, blk_ln1_b + l * ND, Zbuf, twid);
        transpose_bt_kernel<<<dim3(NT / 32, ND / 32, NB), 256, 0, stream>>>(Zbuf, PTbuf);
        fft_t2048_kernel<<<dim3(NB, 257), 256, 0, stream>>>(PTbuf, Mtbuf, twid);
        addt_ln_kernel<<<dim3(NT / 16, NB), 256, 0, stream>>>(
            Mtbuf, xA, blk_ln2_g + l * ND, blk_ln2_b + l * ND, ybf);
        mfma_gemm<1, 0, 1, 1><<<dim3(NM / 256, NH / 128), 512, 0, stream>>>(
            ybf, ND, blkw1t + (size_t)l * ND * NH, blk_b1 + l * NH, hmlp, ND, NH);
        mfma_gemm<0, 1, 0, 1><<<dim3(NM / 256, ND / 128), 512, 0, stream>>>(
            hmlp, NH, blkw2t + (size_t)l * ND * NH, blk_b2 + l * ND, xA, NH, ND);
    }

    // 4) final norm + head (outwt generated late into dead hmlp slot)
    ln_kernel<ND, 0, 1><<<NM, 256, 0, stream>>>(xA, norm_g, norm_b, ybf);
    wconv_kernel<<<dim3(256 / 32, ND / 32, 1), 256, 0, stream>>>(out_w, outwt, ND, 256);
    mfma_gemm<0, 0, 0, 1><<<dim3(NM / 256, 256 / 128), 512, 0, stream>>>(
        ybf, ND, outwt, out_b, out, ND, 256);
}

// Round 20
// 2728.908 us; speedup vs baseline: 1.0270x; 1.0270x over previous
//
#include <hip/hip_runtime.h>
#include <cmath>

typedef unsigned short u16;
typedef unsigned int u32;

// Problem constants
constexpr int NB = 16;            // batch
constexpr int NT = 2048;          // seq len
constexpr int ND = 512;           // embed dim
constexpr int NL = 6;             // layers
constexpr int NH = 1024;          // mlp hidden
constexpr int NK = 256;           // freq bands kept
constexpr int NM = NB * NT;       // 32768 rows

constexpr float PI2 = 6.283185307179586f;

typedef short bf16x8 __attribute__((ext_vector_type(8)));
typedef float f32x4 __attribute__((ext_vector_type(4)));

__device__ __forceinline__ float gelu_exact(float v) {
    return 0.5f * v * (1.0f + erff(v * 0.70710678118654752f));
}

__device__ __forceinline__ u16 f2bf(float f) {
    union { float f; u32 u; } v; v.f = f;
    u32 r = v.u + 0x7FFFu + ((v.u >> 16) & 1u);
    return (u16)(r >> 16);
}

__device__ __forceinline__ float bf2f(u16 h) {
    union { u32 u; float f; } v; v.u = ((u32)h) << 16;
    return v.f;
}

__device__ __forceinline__ float block_sum256(float val, float* lds4) {
#pragma unroll
    for (int o = 32; o > 0; o >>= 1) val += __shfl_down(val, o);
    int lane = threadIdx.x & 63, wid = threadIdx.x >> 6;
    if (lane == 0) lds4[wid] = val;
    __syncthreads();
    float t = lds4[0] + lds4[1] + lds4[2] + lds4[3];
    __syncthreads();
    return t;
}

// XCD-chunked block swizzle (R12-proven). Tile size passed in.
__device__ __forceinline__ void swz_block_t(int bm, int& row0, int& col0) {
    int nwg = gridDim.x * gridDim.y;
    int wg = blockIdx.x + blockIdx.y * gridDim.x;
    int L = wg;
    if ((nwg & 7) == 0) {
        int q = nwg >> 3;
        L = (wg & 7) * q + (wg >> 3);
    }
    int ncol = gridDim.y;
    row0 = (L / ncol) * bm;
    col0 = (L % ncol) * 128;
}

// ---------------- twiddle table: entry (h-1)+k = exp(-i*pi*k/h) --------------
__global__ void twiddle_kernel(float2* __restrict__ tw) {
    int idx = blockIdx.x * 256 + threadIdx.x;
    if (idx < 2047) {
        u32 v = idx + 1;
        u32 h = 1u << (31 - __clz(v));
        u32 k = v - h;
        float a = -(float)M_PI * (float)k / (float)h;
        tw[idx] = make_float2(cosf(a), sinf(a));
    }
}

// ---------------- K1: direct DFT of byte signal, 16x256 bins -----------------
__global__ void dft_kernel(const int* __restrict__ bytes, const float* __restrict__ fb,
                           float* __restrict__ mag, float* __restrict__ cph,
                           float* __restrict__ sph) {
    __shared__ float lr[4], li[4];
    int b = blockIdx.x, f = blockIdx.y;
    float re = 0.f, im = 0.f;
    for (int t = threadIdx.x; t < NT; t += 256) {
        float s = (float)bytes[b * NT + t] * (1.0f / 127.5f) - 1.0f;
        int idx = (t * f) & (NT - 1);
        float a = (float)idx * (PI2 / NT);
        float sn, cs;
        sincosf(a, &sn, &cs);
        re += s * cs;
        im -= s * sn;
    }
#pragma unroll
    for (int o = 32; o > 0; o >>= 1) {
        re += __shfl_down(re, o);
        im += __shfl_down(im, o);
    }
    int lane = threadIdx.x & 63, wid = threadIdx.x >> 6;
    if (lane == 0) { lr[wid] = re; li[wid] = im; }
    __syncthreads();
    if (threadIdx.x == 0) {
        float R = lr[0] + lr[1] + lr[2] + lr[3];
        float I = li[0] + li[1] + li[2] + li[3];
        float m = sqrtf(R * R + I * I);
        mag[b * NK + f] = m * fb[f];
        float inv = (m > 0.f) ? 1.0f / m : 0.f;
        cph[b * NK + f] = (m > 0.f) ? R * inv : 1.0f;  // cos(angle)
        sph[b * NK + f] = I * inv;                     // sin(angle)
    }
}

// -------- K2: spectral features [mag | sin(phase)] -> split bf16 hi/lo -------
__global__ void feats_split_kernel(const float* __restrict__ mag,
                                   const float* __restrict__ cph,
                                   const float* __restrict__ sph,
                                   u16* __restrict__ hi, u16* __restrict__ lo) {
    int idx = blockIdx.x * 256 + threadIdx.x;
    int d = idx & (ND - 1);
    int m = idx >> 9;
    int b = m >> 11, t = m & (NT - 1);
    float v;
    if (d < NK) {
        v = mag[b * NK + d];
    } else {
        int f = d - NK;
        int a = (t * f) & (NT - 1);
        float sn, cs;
        sincosf((float)a * (PI2 / NT), &sn, &cs);
        v = sph[b * NK + f] * cs + cph[b * NK + f] * sn;  // sin(bp + theta)
    }
    u16 h = f2bf(v);
    hi[idx] = h;
    lo[idx] = f2bf(v - bf2f(h));
}

// ------- LayerNorm: OBF 0=f32 out, 1=bf16 out, 2=split hi/lo pair out --------
template <int NV, int GELU, int OBF>
__global__ void ln_kernel(const float* __restrict__ in, const float* __restrict__ g,
                          const float* __restrict__ bta, void* __restrict__ outv) {
    __shared__ float lds4[4];
    constexpr int NE = NV / 256;
    size_t row = blockIdx.x;
    const float* p = in + row * NV;
    float v[NE];
    float sum = 0.f;
#pragma unroll
    for (int i = 0; i < NE; ++i) {
        v[i] = p[threadIdx.x + 256 * i];
        sum += v[i];
    }
    sum = block_sum256(sum, lds4);
    float mean = sum * (1.0f / NV);
    float sq = 0.f;
#pragma unroll
    for (int i = 0; i < NE; ++i) {
        float d = v[i] - mean;
        sq += d * d;
    }
    sq = block_sum256(sq, lds4);
    float inv = rsqrtf(sq * (1.0f / NV) + 1e-5f);
#pragma unroll
    for (int i = 0; i < NE; ++i) {
        int c = threadIdx.x + 256 * i;
        float r = (v[i] - mean) * inv * g[c] + bta[c];
        if (GELU) r = gelu_exact(r);
        if (OBF == 2) {
            u16* o = (u16*)outv + row * (2 * NV);
            u16 hb = f2bf(r);
            o[c] = hb;
            o[NV + c] = f2bf(r - bf2f(hb));
        } else if (OBF == 1) {
            ((u16*)outv)[row * NV + c] = f2bf(r);
        } else {
            ((float*)outv)[row * NV + c] = r;
        }
    }
}

// ------- fused LN + 512-pt FFT along D, WAVE-PER-ROW (4 rows/block) ----------
__global__ void ln_fftd_kernel(const float* __restrict__ x, const float* __restrict__ g,
                               const float* __restrict__ bta, float* __restrict__ P,
                               const float2* __restrict__ twid) {
    __shared__ float sr[4][512], si[4][512];  // 16 KiB
    int wv = threadIdx.x >> 6, lane = threadIdx.x & 63;
    int rlocal = blockIdx.x * 4 + wv;
    const float* p = x + (size_t)rlocal * ND;
    float v[8];
    float s = 0.f;
#pragma unroll
    for (int j = 0; j < 8; ++j) { v[j] = p[lane + 64 * j]; s += v[j]; }
#pragma unroll
    for (int o = 32; o > 0; o >>= 1) s += __shfl_down(s, o);
    s = __shfl(s, 0);
    float mean = s * (1.0f / ND);
    float q = 0.f;
#pragma unroll
    for (int j = 0; j < 8; ++j) { float d = v[j] - mean; q += d * d; }
#pragma unroll
    for (int o = 32; o > 0; o >>= 1) q += __shfl_down(q, o);
    q = __shfl(q, 0);
    float inv = rsqrtf(q * (1.0f / ND) + 1e-5f);
#pragma unroll
    for (int j = 0; j < 8; ++j) {
        int i = lane + 64 * j;
        int r = __brev((unsigned)i) >> 23;  // 9-bit reverse
        sr[wv][r] = (v[j] - mean) * inv * g[i] + bta[i];
        si[wv][r] = 0.f;
    }
    for (int len = 2; len <= 512; len <<= 1) {
        int half = len >> 1;
#pragma unroll
        for (int qq = lane; qq < 256; qq += 64) {
            int k = qq & (half - 1);
            int j = ((qq - k) << 1) + k;
            float2 tw = twid[(half - 1) + k];
            float cs = tw.x, sn = tw.y;
            float ur = sr[wv][j], ui = si[wv][j];
            float vr = sr[wv][j + half], vi = si[wv][j + half];
            float tr = vr * cs - vi * sn;
            float ti = vr * sn + vi * cs;
            sr[wv][j] = ur + tr;
            si[wv][j] = ui + ti;
            sr[wv][j + half] = ur - tr;
            si[wv][j + half] = ui - ti;
        }
    }
    float* out = P + (size_t)rlocal * ND;
#pragma unroll
    for (int j = 0; j < 8; ++j) {
        int i = lane + 64 * j;
        out[i] = (i <= 256) ? sr[wv][i] : si[wv][i - 256];
    }
}

// ---------------- tiled transpose: PT[b][idx][t] = P[b*T+t][idx] -------------
__global__ void transpose_bt_kernel(const float* __restrict__ P, float* __restrict__ PT) {
    __shared__ float tile[32][33];
    int b = blockIdx.z, t0 = blockIdx.x * 32, d0 = blockIdx.y * 32;
    int j = threadIdx.x & 31, i0 = threadIdx.x >> 5;
    for (int i = i0; i < 32; i += 8)
        tile[i][j] = P[((size_t)(b * NT + t0 + i)) * ND + d0 + j];
    __syncthreads();
    for (int i = i0; i < 32; i += 8)
        PT[((size_t)(b * ND + d0 + i)) * NT + t0 + j] = tile[j][i];
}

// ---------------- FFT along T (2048-pt per column d=0..256) ------------------
__global__ void fft_t2048_kernel(const float* __restrict__ PT, float* __restrict__ Mt,
                                 const float2* __restrict__ twid) {
    __shared__ float sr[2048], si[2048];  // 16 KiB
    int b = blockIdx.x;
    int d = blockIdx.y;  // 0..256
    const float* zr = PT + ((size_t)(b * ND + d)) * NT;
    const float* zi = PT + ((size_t)(b * ND + 256 + d)) * NT;  // valid for 1<=d<=255
    bool has_im = (d != 0) && (d != 256);
    for (int t = threadIdx.x; t < 2048; t += 256) {
        int r = __brev((unsigned)t) >> 21;  // 11-bit reverse
        sr[r] = zr[t];
        si[r] = has_im ? zi[t] : 0.f;
    }
    __syncthreads();
    for (int len = 2; len <= 2048; len <<= 1) {
        int half = len >> 1;
        for (int q = threadIdx.x; q < 1024; q += 256) {
            int k = q & (half - 1);
            int j = ((q - k) << 1) + k;
            float2 tw = twid[(half - 1) + k];
            float cs = tw.x, sn = tw.y;
            float ur = sr[j], ui = si[j];
            float vr = sr[j + half], vi = si[j + half];
            float tr = vr * cs - vi * sn;
            float ti = vr * sn + vi * cs;
            sr[j] = ur + tr;
            si[j] = ui + ti;
            sr[j + half] = ur - tr;
            si[j + half] = ui - ti;
        }
        __syncthreads();
    }
    float* m0 = Mt + ((size_t)(b * ND + d)) * NT;
    for (int t = threadIdx.x; t < 2048; t += 256) m0[t] = sr[t];
    if (has_im) {
        float* m1 = Mt + ((size_t)(b * ND + (512 - d))) * NT;
        for (int t = threadIdx.x; t < 2048; t += 256) m1[t] = sr[(2048 - t) & 2047];
    }
}

// ------- FUSED: x[b,t,d] += Mt[b,d,t]; then LN2 -> ybf (bf16) ---------------
__global__ void addt_ln_kernel(const float* __restrict__ Mt, float* __restrict__ x,
                               const float* __restrict__ g, const float* __restrict__ bta,
                               u16* __restrict__ yb) {
    __shared__ float tile[512 * 17];  // [d][tloc] stride 17 (34.8KB, 2-way banks)
    int b = blockIdx.y, t0 = blockIdx.x * 16;
    int tid = threadIdx.x;
    for (int lin = tid; lin < 512 * 16; lin += 256) {
        int tloc = lin & 15, d = lin >> 4;
        tile[d * 17 + tloc] = Mt[((size_t)(b * ND + d)) * NT + t0 + tloc];
    }
    __syncthreads();
    int lane = tid & 63, wv = tid >> 6;
#pragma unroll
    for (int rr = 0; rr < 4; ++rr) {
        int tloc = wv * 4 + rr;
        size_t row = (size_t)(b * NT + t0 + tloc);
        float v[8];
        float s = 0.f;
#pragma unroll
        for (int e = 0; e < 8; ++e) {
            int d = lane + 64 * e;
            v[e] = x[row * ND + d] + tile[d * 17 + tloc];
            s += v[e];
        }
#pragma unroll
        for (int o = 32; o > 0; o >>= 1) s += __shfl_down(s, o);
        s = __shfl(s, 0);
        float mean = s * (1.0f / ND);
        float q = 0.f;
#pragma unroll
        for (int e = 0; e < 8; ++e) { float d2 = v[e] - mean; q += d2 * d2; }
#pragma unroll
        for (int o = 32; o > 0; o >>= 1) q += __shfl_down(q, o);
        q = __shfl(q, 0);
        float inv = rsqrtf(q * (1.0f / ND) + 1e-5f);
#pragma unroll
        for (int e = 0; e < 8; ++e) {
            int d = lane + 64 * e;
            x[row * ND + d] = v[e];
            yb[row * ND + d] = f2bf((v[e] - mean) * inv * g[d] + bta[d]);
        }
    }
}

// ---------------- weight transpose + f32->bf16: Wt[n][k] = W[k][n] -----------
__global__ void wconv_kernel(const float* __restrict__ W, u16* __restrict__ Wt,
                             int K, int N) {
    __shared__ float tile[32][33];
    size_t moff = (size_t)blockIdx.z * K * N;
    int n0 = blockIdx.x * 32, k0 = blockIdx.y * 32;
    int j = threadIdx.x & 31, i0 = threadIdx.x >> 5;
    for (int i = i0; i < 32; i += 8)
        tile[i][j] = W[moff + (size_t)(k0 + i) * N + n0 + j];
    __syncthreads();
    for (int i = i0; i < 32; i += 8)
        Wt[moff + (size_t)(n0 + i) * K + k0 + j] = f2bf(tile[j][i]);
}

// ------- bf16 MFMA GEMM: 256x128 tile, 8 waves, 2-buffer gload_lds -----------
template <int GELU, int ACC, int OBF, int ADDB>
__global__ __launch_bounds__(512) void mfma_gemm(
    const u16* __restrict__ A, int lda, const u16* __restrict__ Wt,
    const float* __restrict__ bias, void* __restrict__ Cv, int Kd, int Nd) {
    __shared__ __align__(16) u16 Al[2][8192];
    __shared__ __align__(16) u16 Bl[2][4096];
    int tid = threadIdx.x;
    int row0, col0;
    swz_block_t(256, row0, col0);
    int lane = tid & 63, w = tid >> 6;
    int wr = w >> 1, wc = w & 1;      // wr 0..3, wc 0..1
    int kg = lane >> 4, ln16 = lane & 15;

    f32x4 acc[4][4] = {};

    auto stage = [&](int buf, int t) {
        int k0 = t << 5;
#pragma unroll
        for (int i = 0; i < 2; ++i) {   // A: 1024 slots, 512 threads
            int s = i * 512 + tid;
            int skg = s >> 8, r = s & 255;
            const u16* ga = A + (size_t)(row0 + r) * lda + k0 + skg * 8;
            __builtin_amdgcn_global_load_lds(
                (const __attribute__((address_space(1))) void*)ga,
                (__attribute__((address_space(3))) void*)&Al[buf][s * 8], 16, 0, 0);
        }
        {                               // B: 512 slots
            int s = tid;
            int skg = s >> 7, r = s & 127;
            const u16* gb = Wt + (size_t)(col0 + r) * Kd + k0 + skg * 8;
            __builtin_amdgcn_global_load_lds(
                (const __attribute__((address_space(1))) void*)gb,
                (__attribute__((address_space(3))) void*)&Bl[buf][s * 8], 16, 0, 0);
        }
    };
    auto compute = [&](int buf) {
        bf16x8 af[4], bfr[4];
#pragma unroll
        for (int mi = 0; mi < 4; ++mi)
            af[mi] = *(const bf16x8*)&Al[buf][(kg * 256 + wr * 64 + mi * 16 + ln16) * 8];
#pragma unroll
        for (int ni = 0; ni < 4; ++ni)
            bfr[ni] = *(const bf16x8*)&Bl[buf][(kg * 128 + wc * 64 + ni * 16 + ln16) * 8];
#pragma unroll
        for (int mi = 0; mi < 4; ++mi)
#pragma unroll
            for (int ni = 0; ni < 4; ++ni)
                acc[mi][ni] = __builtin_amdgcn_mfma_f32_16x16x32_bf16(
                    af[mi], bfr[ni], acc[mi][ni], 0, 0, 0);
    };

    int nt = Kd >> 5;
    stage(0, 0);
    __syncthreads();
    int cur = 0;
    for (int t = 1; t < nt; ++t) {
        stage(cur ^ 1, t);
        compute(cur);
        __syncthreads();
        cur ^= 1;
    }
    compute(cur);

#pragma unroll
    for (int mi = 0; mi < 4; ++mi) {
#pragma unroll
        for (int ni = 0; ni < 4; ++ni) {
            int col = col0 + wc * 64 + ni * 16 + ln16;
            float bv = ADDB ? bias[col] : 0.f;
#pragma unroll
            for (int j = 0; j < 4; ++j) {
                int row = row0 + wr * 64 + mi * 16 + kg * 4 + j;
                float v = acc[mi][ni][j] + bv;
                if (GELU) v = gelu_exact(v);
                size_t o = (size_t)row * Nd + col;
                if (OBF) {
                    ((u16*)Cv)[o] = f2bf(v);
                } else {
                    float* C = (float*)Cv;
                    if (ACC) v += C[o];
                    C[o] = v;
                }
            }
        }
    }
}

// ------- fused split-bf16 GEMM: 128x128, 3-buffer counted-vmcnt (R12) --------
// (R12/R18-proven 138us config: the 3-deep pipeline is the operative lever.)
__global__ __launch_bounds__(256) void mfma_gemm2(
    const u16* __restrict__ Ahi, const u16* __restrict__ Alo, int lda,
    const u16* __restrict__ Wt, const float* __restrict__ bias,
    float* __restrict__ C, int Kd, int Nd) {
    __shared__ __align__(16) u16 Ah[3][4096];
    __shared__ __align__(16) u16 Al2[3][4096];
    __shared__ __align__(16) u16 Bl[3][4096];
    int tid = threadIdx.x;
    int row0, col0;
    swz_block_t(128, row0, col0);
    int lane = tid & 63, w = tid >> 6;
    int wr = w >> 1, wc = w & 1;
    int kg = lane >> 4, ln16 = lane & 15;

    f32x4 acc[4][4] = {};

    auto stage = [&](int buf, int t) {
        int k0 = t << 5;
#pragma unroll
        for (int i = 0; i < 2; ++i) {
            int s = i * 256 + tid;
            int skg = s >> 7, r = s & 127;
            size_t aoff = (size_t)(row0 + r) * lda + k0 + skg * 8;
            __builtin_amdgcn_global_load_lds(
                (const __attribute__((address_space(1))) void*)(Ahi + aoff),
                (__attribute__((address_space(3))) void*)&Ah[buf][s * 8], 16, 0, 0);
            __builtin_amdgcn_global_load_lds(
                (const __attribute__((address_space(1))) void*)(Alo + aoff),
                (__attribute__((address_space(3))) void*)&Al2[buf][s * 8], 16, 0, 0);
            const u16* gb = Wt + (size_t)(col0 + r) * Kd + k0 + skg * 8;
            __builtin_amdgcn_global_load_lds(
                (const __attribute__((address_space(1))) void*)gb,
                (__attribute__((address_space(3))) void*)&Bl[buf][s * 8], 16, 0, 0);
        }
    };
    auto compute = [&](int buf) {
        bf16x8 ah[4], al[4], bfr[4];
#pragma unroll
        for (int mi = 0; mi < 4; ++mi) {
            int sl = (kg * 128 + wr * 64 + mi * 16 + ln16) * 8;
            ah[mi] = *(const bf16x8*)&Ah[buf][sl];
            al[mi] = *(const bf16x8*)&Al2[buf][sl];
        }
#pragma unroll
        for (int ni = 0; ni < 4; ++ni)
            bfr[ni] = *(const bf16x8*)&Bl[buf][(kg * 128 + wc * 64 + ni * 16 + ln16) * 8];
#pragma unroll
        for (int mi = 0; mi < 4; ++mi)
#pragma unroll
            for (int ni = 0; ni < 4; ++ni) {
                acc[mi][ni] = __builtin_amdgcn_mfma_f32_16x16x32_bf16(
                    ah[mi], bfr[ni], acc[mi][ni], 0, 0, 0);
                acc[mi][ni] = __builtin_amdgcn_mfma_f32_16x16x32_bf16(
                    al[mi], bfr[ni], acc[mi][ni], 0, 0, 0);
            }
    };

    int nt = Kd >> 5;
    stage(0, 0);
    stage(1, 1);
    for (int t = 0; t < nt; ++t) {
        if (t + 1 < nt) asm volatile("s_waitcnt vmcnt(6)" ::: "memory");
        else            asm volatile("s_waitcnt vmcnt(0)" ::: "memory");
        __builtin_amdgcn_sched_barrier(0);
        __builtin_amdgcn_s_barrier();
        __builtin_amdgcn_sched_barrier(0);
        if (t + 2 < nt) stage((t + 2) % 3, t + 2);
        compute(t % 3);
    }

#pragma unroll
    for (int mi = 0; mi < 4; ++mi) {
#pragma unroll
        for (int ni = 0; ni < 4; ++ni) {
            int col = col0 + wc * 64 + ni * 16 + ln16;
            float bv = bias[col];
#pragma unroll
            for (int j = 0; j < 4; ++j) {
                int row = row0 + wr * 64 + mi * 16 + kg * 4 + j;
                C[(size_t)row * Nd + col] = acc[mi][ni][j] + bv;
            }
        }
    }
}

extern "C" void kernel_launch(void* const* d_in, const int* in_sizes, int n_in,
                              void* d_out, int out_size, void* d_ws, size_t ws_size,
                              hipStream_t stream) {
    const int* byte_ids     = (const int*)d_in[0];
    const float* freq_bands = (const float*)d_in[1];
    const float* fp_w1   = (const float*)d_in[2];
    const float* fp_b1   = (const float*)d_in[3];
    const float* fp_ln_g = (const float*)d_in[4];
    const float* fp_ln_b = (const float*)d_in[5];
    const float* fp_w2   = (const float*)d_in[6];
    const float* fp_b2   = (const float*)d_in[7];
    const float* blk_ln1_g = (const float*)d_in[8];
    const float* blk_ln1_b = (const float*)d_in[9];
    const float* blk_ln2_g = (const float*)d_in[10];
    const float* blk_ln2_b = (const float*)d_in[11];
    const float* blk_w1  = (const float*)d_in[12];
    const float* blk_b1  = (const float*)d_in[13];
    const float* blk_w2  = (const float*)d_in[14];
    const float* blk_b2  = (const float*)d_in[15];
    const float* norm_g  = (const float*)d_in[16];
    const float* norm_b  = (const float*)d_in[17];
    const float* out_w   = (const float*)d_in[18];
    const float* out_b   = (const float*)d_in[19];
    float* out = (float*)d_out;
    char* base = (char*)d_ws;
    char* obase = (char*)d_out;
    const size_t MB = 1048576;

    // ---- Workspace map (192 MiB, full-batch mixing) — same as R16-R18:
    u16* fhi     = (u16*)base;
    u16* flo     = (u16*)(base + 32 * MB);
    float* xA    = (float*)base;
    float* hfp   = (float*)(base + 64 * MB);
    u16* h2      = (u16*)hfp;
    float* Zbuf  = (float*)(base + 64 * MB);     // [M,512] f32 (64MB)
    float* PTbuf = (float*)(base + 128 * MB);    // [B,512,2048] f32 (64MB)
    float* Mtbuf = Zbuf;
    u16* hmlp    = (u16*)(base + 64 * MB);       // [M,1024] bf16
    u16* ybf     = (u16*)(base + 128 * MB);      // [M,512] bf16
    u16* outwt   = (u16*)(base + 64 * MB);       // [256][512] (written late)
    u16* fpw1t   = (u16*)obase;
    u16* fpw2t   = (u16*)(obase + 1 * MB);
    float* mag   = (float*)(obase + 2 * MB);
    float* cph   = mag + NB * NK;
    float* sph   = cph + NB * NK;
    float2* twid = (float2*)(obase + 4 * MB);
    u16* blkw1t  = (u16*)(obase + 6 * MB);       // 6 x [1024][512]
    u16* blkw2t  = (u16*)(obase + 12 * MB);      // 6 x [512][1024]

    // 0) twiddle table
    twiddle_kernel<<<8, 256, 0, stream>>>(twid);

    // 1) spectral embedding -> split bf16 feats
    dft_kernel<<<dim3(NB, NK), 256, 0, stream>>>(byte_ids, freq_bands, mag, cph, sph);
    feats_split_kernel<<<(NM * ND) / 256, 256, 0, stream>>>(mag, cph, sph, fhi, flo);
    wconv_kernel<<<dim3(NH / 32, ND / 32, 1), 256, 0, stream>>>(fp_w1, fpw1t, ND, NH);
    wconv_kernel<<<dim3(ND / 32, NH / 32, 1), 256, 0, stream>>>(fp_w2, fpw2t, NH, ND);
    wconv_kernel<<<dim3(NH / 32, ND / 32, NL), 256, 0, stream>>>(blk_w1, blkw1t, ND, NH);
    wconv_kernel<<<dim3(ND / 32, NH / 32, NL), 256, 0, stream>>>(blk_w2, blkw2t, NH, ND);

    // 2) freq_proj via fused split-bf16 MFMA (128-tile, 3-buffer pipeline)
    mfma_gemm2<<<dim3(NM / 128, NH / 128), 256, 0, stream>>>(
        fhi, flo, ND, fpw1t, fp_b1, hfp, ND, NH);
    ln_kernel<NH, 1, 2><<<NM, 256, 0, stream>>>(hfp, fp_ln_g, fp_ln_b, h2);
    mfma_gemm2<<<dim3(NM / 128, ND / 128), 256, 0, stream>>>(
        h2, h2 + NH, 2 * NH, fpw2t, fp_b2, xA, NH, ND);

    // 3) spectral MLP blocks: full-batch mixing (f32) + MLP bf16 MFMA (256-tile)
    for (int l = 0; l < NL; ++l) {
        ln_fftd_kernel<<<NM / 4, 256, 0, stream>>>(
            xA, blk_ln1_g + l * ND, blk_ln1_b + l * ND, Zbuf, twid);
        transpose_bt_kernel<<<dim3(NT / 32, ND / 32, NB), 256, 0, stream>>>(Zbuf, PTbuf);
        fft_t2048_kernel<<<dim3(NB, 257), 256, 0, stream>>>(PTbuf, Mtbuf, twid);
        addt_ln_kernel<<<dim3(NT / 16, NB), 256, 0, stream>>>(
            Mtbuf, xA, blk_ln2_g + l * ND, blk_ln2_b + l * ND, ybf);
        mfma_gemm<1, 0, 1, 1><<<dim3(NM / 256, NH / 128), 512, 0, stream>>>(
            ybf, ND, blkw1t + (size_t)l * ND * NH, blk_b1 + l * NH, hmlp, ND, NH);
        mfma_gemm<0, 1, 0, 1><<<dim3(NM / 256, ND / 128), 512, 0, stream>>>(
            hmlp, NH, blkw2t + (size_t)l * ND * NH, blk_b2 + l * ND, xA, NH, ND);
    }

    // 4) final norm + head (outwt generated late into dead hmlp slot)
    ln_kernel<ND, 0, 1><<<NM, 256, 0, stream>>>(xA, norm_g, norm_b, ybf);
    wconv_kernel<<<dim3(256 / 32, ND / 32, 1), 256, 0, stream>>>(out_w, outwt, ND, 256);
    mfma_gemm<0, 0, 0, 1><<<dim3(NM / 256, 256 / 128), 512, 0, stream>>>(
        ybf, ND, outwt, out_b, out, ND, 256);
}

// Round 21
// 2711.038 us; speedup vs baseline: 1.0337x; 1.0066x over previous
//
#include <hip/hip_runtime.h>
#include <cmath>

typedef unsigned short u16;
typedef unsigned int u32;

// Problem constants
constexpr int NB = 16;            // batch
constexpr int NT = 2048;          // seq len
constexpr int ND = 512;           // embed dim
constexpr int NL = 6;             // layers
constexpr int NH = 1024;          // mlp hidden
constexpr int NK = 256;           // freq bands kept
constexpr int NM = NB * NT;       // 32768 rows

constexpr float PI2 = 6.283185307179586f;

typedef short bf16x8 __attribute__((ext_vector_type(8)));
typedef float f32x4 __attribute__((ext_vector_type(4)));

__device__ __forceinline__ float gelu_exact(float v) {
    return 0.5f * v * (1.0f + erff(v * 0.70710678118654752f));
}

__device__ __forceinline__ u16 f2bf(float f) {
    union { float f; u32 u; } v; v.f = f;
    u32 r = v.u + 0x7FFFu + ((v.u >> 16) & 1u);
    return (u16)(r >> 16);
}

__device__ __forceinline__ float bf2f(u16 h) {
    union { u32 u; float f; } v; v.u = ((u32)h) << 16;
    return v.f;
}

__device__ __forceinline__ float block_sum256(float val, float* lds4) {
#pragma unroll
    for (int o = 32; o > 0; o >>= 1) val += __shfl_down(val, o);
    int lane = threadIdx.x & 63, wid = threadIdx.x >> 6;
    if (lane == 0) lds4[wid] = val;
    __syncthreads();
    float t = lds4[0] + lds4[1] + lds4[2] + lds4[3];
    __syncthreads();
    return t;
}

// XCD-chunked block swizzle (R12-proven). Tile size passed in.
__device__ __forceinline__ void swz_block_t(int bm, int& row0, int& col0) {
    int nwg = gridDim.x * gridDim.y;
    int wg = blockIdx.x + blockIdx.y * gridDim.x;
    int L = wg;
    if ((nwg & 7) == 0) {
        int q = nwg >> 3;
        L = (wg & 7) * q + (wg >> 3);
    }
    int ncol = gridDim.y;
    row0 = (L / ncol) * bm;
    col0 = (L % ncol) * 128;
}

// ---------------- twiddle table: entry (h-1)+k = exp(-i*pi*k/h) --------------
__global__ void twiddle_kernel(float2* __restrict__ tw) {
    int idx = blockIdx.x * 256 + threadIdx.x;
    if (idx < 2047) {
        u32 v = idx + 1;
        u32 h = 1u << (31 - __clz(v));
        u32 k = v - h;
        float a = -(float)M_PI * (float)k / (float)h;
        tw[idx] = make_float2(cosf(a), sinf(a));
    }
}

// ---------------- K1: direct DFT of byte signal, 16x256 bins -----------------
__global__ void dft_kernel(const int* __restrict__ bytes, const float* __restrict__ fb,
                           float* __restrict__ mag, float* __restrict__ cph,
                           float* __restrict__ sph) {
    __shared__ float lr[4], li[4];
    int b = blockIdx.x, f = blockIdx.y;
    float re = 0.f, im = 0.f;
    for (int t = threadIdx.x; t < NT; t += 256) {
        float s = (float)bytes[b * NT + t] * (1.0f / 127.5f) - 1.0f;
        int idx = (t * f) & (NT - 1);
        float a = (float)idx * (PI2 / NT);
        float sn, cs;
        sincosf(a, &sn, &cs);
        re += s * cs;
        im -= s * sn;
    }
#pragma unroll
    for (int o = 32; o > 0; o >>= 1) {
        re += __shfl_down(re, o);
        im += __shfl_down(im, o);
    }
    int lane = threadIdx.x & 63, wid = threadIdx.x >> 6;
    if (lane == 0) { lr[wid] = re; li[wid] = im; }
    __syncthreads();
    if (threadIdx.x == 0) {
        float R = lr[0] + lr[1] + lr[2] + lr[3];
        float I = li[0] + li[1] + li[2] + li[3];
        float m = sqrtf(R * R + I * I);
        mag[b * NK + f] = m * fb[f];
        float inv = (m > 0.f) ? 1.0f / m : 0.f;
        cph[b * NK + f] = (m > 0.f) ? R * inv : 1.0f;  // cos(angle)
        sph[b * NK + f] = I * inv;                     // sin(angle)
    }
}

// -------- K2: spectral features [mag | sin(phase)] -> split bf16 hi/lo -------
__global__ void feats_split_kernel(const float* __restrict__ mag,
                                   const float* __restrict__ cph,
                                   const float* __restrict__ sph,
                                   u16* __restrict__ hi, u16* __restrict__ lo) {
    int idx = blockIdx.x * 256 + threadIdx.x;
    int d = idx & (ND - 1);
    int m = idx >> 9;
    int b = m >> 11, t = m & (NT - 1);
    float v;
    if (d < NK) {
        v = mag[b * NK + d];
    } else {
        int f = d - NK;
        int a = (t * f) & (NT - 1);
        float sn, cs;
        sincosf((float)a * (PI2 / NT), &sn, &cs);
        v = sph[b * NK + f] * cs + cph[b * NK + f] * sn;  // sin(bp + theta)
    }
    u16 h = f2bf(v);
    hi[idx] = h;
    lo[idx] = f2bf(v - bf2f(h));
}

// ------- LayerNorm: OBF 0=f32 out, 1=bf16 out, 2=split hi/lo pair out --------
template <int NV, int GELU, int OBF>
__global__ void ln_kernel(const float* __restrict__ in, const float* __restrict__ g,
                          const float* __restrict__ bta, void* __restrict__ outv) {
    __shared__ float lds4[4];
    constexpr int NE = NV / 256;
    size_t row = blockIdx.x;
    const float* p = in + row * NV;
    float v[NE];
    float sum = 0.f;
#pragma unroll
    for (int i = 0; i < NE; ++i) {
        v[i] = p[threadIdx.x + 256 * i];
        sum += v[i];
    }
    sum = block_sum256(sum, lds4);
    float mean = sum * (1.0f / NV);
    float sq = 0.f;
#pragma unroll
    for (int i = 0; i < NE; ++i) {
        float d = v[i] - mean;
        sq += d * d;
    }
    sq = block_sum256(sq, lds4);
    float inv = rsqrtf(sq * (1.0f / NV) + 1e-5f);
#pragma unroll
    for (int i = 0; i < NE; ++i) {
        int c = threadIdx.x + 256 * i;
        float r = (v[i] - mean) * inv * g[c] + bta[c];
        if (GELU) r = gelu_exact(r);
        if (OBF == 2) {
            u16* o = (u16*)outv + row * (2 * NV);
            u16 hb = f2bf(r);
            o[c] = hb;
            o[NV + c] = f2bf(r - bf2f(hb));
        } else if (OBF == 1) {
            ((u16*)outv)[row * NV + c] = f2bf(r);
        } else {
            ((float*)outv)[row * NV + c] = r;
        }
    }
}

// ------- fused LN + 512-pt FFT along D, WAVE-PER-ROW (4 rows/block) ----------
__global__ void ln_fftd_kernel(const float* __restrict__ x, const float* __restrict__ g,
                               const float* __restrict__ bta, float* __restrict__ P,
                               const float2* __restrict__ twid) {
    __shared__ float sr[4][512], si[4][512];  // 16 KiB
    int wv = threadIdx.x >> 6, lane = threadIdx.x & 63;
    int rlocal = blockIdx.x * 4 + wv;
    const float* p = x + (size_t)rlocal * ND;
    float v[8];
    float s = 0.f;
#pragma unroll
    for (int j = 0; j < 8; ++j) { v[j] = p[lane + 64 * j]; s += v[j]; }
#pragma unroll
    for (int o = 32; o > 0; o >>= 1) s += __shfl_down(s, o);
    s = __shfl(s, 0);
    float mean = s * (1.0f / ND);
    float q = 0.f;
#pragma unroll
    for (int j = 0; j < 8; ++j) { float d = v[j] - mean; q += d * d; }
#pragma unroll
    for (int o = 32; o > 0; o >>= 1) q += __shfl_down(q, o);
    q = __shfl(q, 0);
    float inv = rsqrtf(q * (1.0f / ND) + 1e-5f);
#pragma unroll
    for (int j = 0; j < 8; ++j) {
        int i = lane + 64 * j;
        int r = __brev((unsigned)i) >> 23;  // 9-bit reverse
        sr[wv][r] = (v[j] - mean) * inv * g[i] + bta[i];
        si[wv][r] = 0.f;
    }
    for (int len = 2; len <= 512; len <<= 1) {
        int half = len >> 1;
#pragma unroll
        for (int qq = lane; qq < 256; qq += 64) {
            int k = qq & (half - 1);
            int j = ((qq - k) << 1) + k;
            float2 tw = twid[(half - 1) + k];
            float cs = tw.x, sn = tw.y;
            float ur = sr[wv][j], ui = si[wv][j];
            float vr = sr[wv][j + half], vi = si[wv][j + half];
            float tr = vr * cs - vi * sn;
            float ti = vr * sn + vi * cs;
            sr[wv][j] = ur + tr;
            si[wv][j] = ui + ti;
            sr[wv][j + half] = ur - tr;
            si[wv][j + half] = ui - ti;
        }
    }
    float* out = P + (size_t)rlocal * ND;
#pragma unroll
    for (int j = 0; j < 8; ++j) {
        int i = lane + 64 * j;
        out[i] = (i <= 256) ? sr[wv][i] : si[wv][i - 256];
    }
}

// ---- FFT along T reading P DIRECTLY (stride-ND gather, XCD d-chunked) -------
// Work remap (wg%8 -> XCD model, R12-proven): XCD x handles d in [32x,32x+32)
// for all b, so each 128B line of P is fully consumed from that XCD's L2.
__global__ void fftt_direct_kernel(const float* __restrict__ P, float* __restrict__ Mt,
                                   const float2* __restrict__ twid) {
    __shared__ float sr[2048], si[2048];  // 16 KiB
    int wg = blockIdx.x;
    int x = wg & 7, p = wg >> 3;
    int b, d;
    if (p < 512) { d = x * 32 + (p & 31); b = p >> 5; }
    else         { d = 256; b = x * 2 + (p - 512); }
    const float* pr = P + (size_t)b * NT * ND + d;
    const float* pi = P + (size_t)b * NT * ND + 256 + d;
    bool has_im = (d != 0) && (d != 256);
    for (int t = threadIdx.x; t < 2048; t += 256) {
        int r = __brev((unsigned)t) >> 21;  // 11-bit reverse
        sr[r] = pr[(size_t)t * ND];
        si[r] = has_im ? pi[(size_t)t * ND] : 0.f;
    }
    __syncthreads();
    for (int len = 2; len <= 2048; len <<= 1) {
        int half = len >> 1;
        for (int q = threadIdx.x; q < 1024; q += 256) {
            int k = q & (half - 1);
            int j = ((q - k) << 1) + k;
            float2 tw = twid[(half - 1) + k];
            float cs = tw.x, sn = tw.y;
            float ur = sr[j], ui = si[j];
            float vr = sr[j + half], vi = si[j + half];
            float tr = vr * cs - vi * sn;
            float ti = vr * sn + vi * cs;
            sr[j] = ur + tr;
            si[j] = ui + ti;
            sr[j + half] = ur - tr;
            si[j + half] = ui - ti;
        }
        __syncthreads();
    }
    float* m0 = Mt + ((size_t)(b * ND + d)) * NT;
    for (int t = threadIdx.x; t < 2048; t += 256) m0[t] = sr[t];
    if (has_im) {
        float* m1 = Mt + ((size_t)(b * ND + (512 - d))) * NT;
        for (int t = threadIdx.x; t < 2048; t += 256) m1[t] = sr[(2048 - t) & 2047];
    }
}

// ------- FUSED: x[b,t,d] += Mt[b,d,t]; then LN2 -> ybf (bf16) ---------------
__global__ void addt_ln_kernel(const float* __restrict__ Mt, float* __restrict__ x,
                               const float* __restrict__ g, const float* __restrict__ bta,
                               u16* __restrict__ yb) {
    __shared__ float tile[512 * 17];  // [d][tloc] stride 17 (34.8KB, 2-way banks)
    int b = blockIdx.y, t0 = blockIdx.x * 16;
    int tid = threadIdx.x;
    for (int lin = tid; lin < 512 * 16; lin += 256) {
        int tloc = lin & 15, d = lin >> 4;
        tile[d * 17 + tloc] = Mt[((size_t)(b * ND + d)) * NT + t0 + tloc];
    }
    __syncthreads();
    int lane = tid & 63, wv = tid >> 6;
#pragma unroll
    for (int rr = 0; rr < 4; ++rr) {
        int tloc = wv * 4 + rr;
        size_t row = (size_t)(b * NT + t0 + tloc);
        float v[8];
        float s = 0.f;
#pragma unroll
        for (int e = 0; e < 8; ++e) {
            int d = lane + 64 * e;
            v[e] = x[row * ND + d] + tile[d * 17 + tloc];
            s += v[e];
        }
#pragma unroll
        for (int o = 32; o > 0; o >>= 1) s += __shfl_down(s, o);
        s = __shfl(s, 0);
        float mean = s * (1.0f / ND);
        float q = 0.f;
#pragma unroll
        for (int e = 0; e < 8; ++e) { float d2 = v[e] - mean; q += d2 * d2; }
#pragma unroll
        for (int o = 32; o > 0; o >>= 1) q += __shfl_down(q, o);
        q = __shfl(q, 0);
        float inv = rsqrtf(q * (1.0f / ND) + 1e-5f);
#pragma unroll
        for (int e = 0; e < 8; ++e) {
            int d = lane + 64 * e;
            x[row * ND + d] = v[e];
            yb[row * ND + d] = f2bf((v[e] - mean) * inv * g[d] + bta[d]);
        }
    }
}

// ---------------- weight transpose + f32->bf16: Wt[n][k] = W[k][n] -----------
__global__ void wconv_kernel(const float* __restrict__ W, u16* __restrict__ Wt,
                             int K, int N) {
    __shared__ float tile[32][33];
    size_t moff = (size_t)blockIdx.z * K * N;
    int n0 = blockIdx.x * 32, k0 = blockIdx.y * 32;
    int j = threadIdx.x & 31, i0 = threadIdx.x >> 5;
    for (int i = i0; i < 32; i += 8)
        tile[i][j] = W[moff + (size_t)(k0 + i) * N + n0 + j];
    __syncthreads();
    for (int i = i0; i < 32; i += 8)
        Wt[moff + (size_t)(n0 + i) * K + k0 + j] = f2bf(tile[j][i]);
}

// ------- bf16 MFMA GEMM: 256x128 tile, 8 waves, 2-buffer gload_lds -----------
template <int GELU, int ACC, int OBF, int ADDB>
__global__ __launch_bounds__(512) void mfma_gemm(
    const u16* __restrict__ A, int lda, const u16* __restrict__ Wt,
    const float* __restrict__ bias, void* __restrict__ Cv, int Kd, int Nd) {
    __shared__ __align__(16) u16 Al[2][8192];
    __shared__ __align__(16) u16 Bl[2][4096];
    int tid = threadIdx.x;
    int row0, col0;
    swz_block_t(256, row0, col0);
    int lane = tid & 63, w = tid >> 6;
    int wr = w >> 1, wc = w & 1;      // wr 0..3, wc 0..1
    int kg = lane >> 4, ln16 = lane & 15;

    f32x4 acc[4][4] = {};

    auto stage = [&](int buf, int t) {
        int k0 = t << 5;
#pragma unroll
        for (int i = 0; i < 2; ++i) {   // A: 1024 slots, 512 threads
            int s = i * 512 + tid;
            int skg = s >> 8, r = s & 255;
            const u16* ga = A + (size_t)(row0 + r) * lda + k0 + skg * 8;
            __builtin_amdgcn_global_load_lds(
                (const __attribute__((address_space(1))) void*)ga,
                (__attribute__((address_space(3))) void*)&Al[buf][s * 8], 16, 0, 0);
        }
        {                               // B: 512 slots
            int s = tid;
            int skg = s >> 7, r = s & 127;
            const u16* gb = Wt + (size_t)(col0 + r) * Kd + k0 + skg * 8;
            __builtin_amdgcn_global_load_lds(
                (const __attribute__((address_space(1))) void*)gb,
                (__attribute__((address_space(3))) void*)&Bl[buf][s * 8], 16, 0, 0);
        }
    };
    auto compute = [&](int buf) {
        bf16x8 af[4], bfr[4];
#pragma unroll
        for (int mi = 0; mi < 4; ++mi)
            af[mi] = *(const bf16x8*)&Al[buf][(kg * 256 + wr * 64 + mi * 16 + ln16) * 8];
#pragma unroll
        for (int ni = 0; ni < 4; ++ni)
            bfr[ni] = *(const bf16x8*)&Bl[buf][(kg * 128 + wc * 64 + ni * 16 + ln16) * 8];
#pragma unroll
        for (int mi = 0; mi < 4; ++mi)
#pragma unroll
            for (int ni = 0; ni < 4; ++ni)
                acc[mi][ni] = __builtin_amdgcn_mfma_f32_16x16x32_bf16(
                    af[mi], bfr[ni], acc[mi][ni], 0, 0, 0);
    };

    int nt = Kd >> 5;
    stage(0, 0);
    __syncthreads();
    int cur = 0;
    for (int t = 1; t < nt; ++t) {
        stage(cur ^ 1, t);
        compute(cur);
        __syncthreads();
        cur ^= 1;
    }
    compute(cur);

#pragma unroll
    for (int mi = 0; mi < 4; ++mi) {
#pragma unroll
        for (int ni = 0; ni < 4; ++ni) {
            int col = col0 + wc * 64 + ni * 16 + ln16;
            float bv = ADDB ? bias[col] : 0.f;
#pragma unroll
            for (int j = 0; j < 4; ++j) {
                int row = row0 + wr * 64 + mi * 16 + kg * 4 + j;
                float v = acc[mi][ni][j] + bv;
                if (GELU) v = gelu_exact(v);
                size_t o = (size_t)row * Nd + col;
                if (OBF) {
                    ((u16*)Cv)[o] = f2bf(v);
                } else {
                    float* C = (float*)Cv;
                    if (ACC) v += C[o];
                    C[o] = v;
                }
            }
        }
    }
}

// ------- fused split-bf16 GEMM: 128x128, 3-buffer counted-vmcnt (R12) --------
__global__ __launch_bounds__(256) void mfma_gemm2(
    const u16* __restrict__ Ahi, const u16* __restrict__ Alo, int lda,
    const u16* __restrict__ Wt, const float* __restrict__ bias,
    float* __restrict__ C, int Kd, int Nd) {
    __shared__ __align__(16) u16 Ah[3][4096];
    __shared__ __align__(16) u16 Al2[3][4096];
    __shared__ __align__(16) u16 Bl[3][4096];
    int tid = threadIdx.x;
    int row0, col0;
    swz_block_t(128, row0, col0);
    int lane = tid & 63, w = tid >> 6;
    int wr = w >> 1, wc = w & 1;
    int kg = lane >> 4, ln16 = lane & 15;

    f32x4 acc[4][4] = {};

    auto stage = [&](int buf, int t) {
        int k0 = t << 5;
#pragma unroll
        for (int i = 0; i < 2; ++i) {
            int s = i * 256 + tid;
            int skg = s >> 7, r = s & 127;
            size_t aoff = (size_t)(row0 + r) * lda + k0 + skg * 8;
            __builtin_amdgcn_global_load_lds(
                (const __attribute__((address_space(1))) void*)(Ahi + aoff),
                (__attribute__((address_space(3))) void*)&Ah[buf][s * 8], 16, 0, 0);
            __builtin_amdgcn_global_load_lds(
                (const __attribute__((address_space(1))) void*)(Alo + aoff),
                (__attribute__((address_space(3))) void*)&Al2[buf][s * 8], 16, 0, 0);
            const u16* gb = Wt + (size_t)(col0 + r) * Kd + k0 + skg * 8;
            __builtin_amdgcn_global_load_lds(
                (const __attribute__((address_space(1))) void*)gb,
                (__attribute__((address_space(3))) void*)&Bl[buf][s * 8], 16, 0, 0);
        }
    };
    auto compute = [&](int buf) {
        bf16x8 ah[4], al[4], bfr[4];
#pragma unroll
        for (int mi = 0; mi < 4; ++mi) {
            int sl = (kg * 128 + wr * 64 + mi * 16 + ln16) * 8;
            ah[mi] = *(const bf16x8*)&Ah[buf][sl];
            al[mi] = *(const bf16x8*)&Al2[buf][sl];
        }
#pragma unroll
        for (int ni = 0; ni < 4; ++ni)
            bfr[ni] = *(const bf16x8*)&Bl[buf][(kg * 128 + wc * 64 + ni * 16 + ln16) * 8];
#pragma unroll
        for (int mi = 0; mi < 4; ++mi)
#pragma unroll
            for (int ni = 0; ni < 4; ++ni) {
                acc[mi][ni] = __builtin_amdgcn_mfma_f32_16x16x32_bf16(
                    ah[mi], bfr[ni], acc[mi][ni], 0, 0, 0);
                acc[mi][ni] = __builtin_amdgcn_mfma_f32_16x16x32_bf16(
                    al[mi], bfr[ni], acc[mi][ni], 0, 0, 0);
            }
    };

    int nt = Kd >> 5;
    stage(0, 0);
    stage(1, 1);
    for (int t = 0; t < nt; ++t) {
        if (t + 1 < nt) asm volatile("s_waitcnt vmcnt(6)" ::: "memory");
        else            asm volatile("s_waitcnt vmcnt(0)" ::: "memory");
        __builtin_amdgcn_sched_barrier(0);
        __builtin_amdgcn_s_barrier();
        __builtin_amdgcn_sched_barrier(0);
        if (t + 2 < nt) stage((t + 2) % 3, t + 2);
        compute(t % 3);
    }

#pragma unroll
    for (int mi = 0; mi < 4; ++mi) {
#pragma unroll
        for (int ni = 0; ni < 4; ++ni) {
            int col = col0 + wc * 64 + ni * 16 + ln16;
            float bv = bias[col];
#pragma unroll
            for (int j = 0; j < 4; ++j) {
                int row = row0 + wr * 64 + mi * 16 + kg * 4 + j;
                C[(size_t)row * Nd + col] = acc[mi][ni][j] + bv;
            }
        }
    }
}

extern "C" void kernel_launch(void* const* d_in, const int* in_sizes, int n_in,
                              void* d_out, int out_size, void* d_ws, size_t ws_size,
                              hipStream_t stream) {
    const int* byte_ids     = (const int*)d_in[0];
    const float* freq_bands = (const float*)d_in[1];
    const float* fp_w1   = (const float*)d_in[2];
    const float* fp_b1   = (const float*)d_in[3];
    const float* fp_ln_g = (const float*)d_in[4];
    const float* fp_ln_b = (const float*)d_in[5];
    const float* fp_w2   = (const float*)d_in[6];
    const float* fp_b2   = (const float*)d_in[7];
    const float* blk_ln1_g = (const float*)d_in[8];
    const float* blk_ln1_b = (const float*)d_in[9];
    const float* blk_ln2_g = (const float*)d_in[10];
    const float* blk_ln2_b = (const float*)d_in[11];
    const float* blk_w1  = (const float*)d_in[12];
    const float* blk_b1  = (const float*)d_in[13];
    const float* blk_w2  = (const float*)d_in[14];
    const float* blk_b2  = (const float*)d_in[15];
    const float* norm_g  = (const float*)d_in[16];
    const float* norm_b  = (const float*)d_in[17];
    const float* out_w   = (const float*)d_in[18];
    const float* out_b   = (const float*)d_in[19];
    float* out = (float*)d_out;
    char* base = (char*)d_ws;
    char* obase = (char*)d_out;
    const size_t MB = 1048576;

    // ---- Workspace map (192 MiB), R21 re-slot (transpose-free mixing):
    // [0,64)    fhi[0,32)+flo[32,64) -> xA f32 (written by G2 after both dead)
    // freq_proj: hfp f32 [64,192) (h2 split in-place)
    // per-layer: P [64,128) -> Mt [128,192); ybf bf16 [64,96) (P dead);
    //            hmlp bf16 [96,160) (Mt dead); outwt [96,96.25) at head time
    u16* fhi     = (u16*)base;
    u16* flo     = (u16*)(base + 32 * MB);
    float* xA    = (float*)base;                 // [M,512] f32 = [0,64)
    float* hfp   = (float*)(base + 64 * MB);     // [M,1024] f32 = [64,192)
    u16* h2      = (u16*)hfp;
    float* Pbuf  = (float*)(base + 64 * MB);     // [M,512] f32 = [64,128)
    float* Mtbuf = (float*)(base + 128 * MB);    // [B,512,2048] f32 = [128,192)
    u16* ybf     = (u16*)(base + 64 * MB);       // [M,512] bf16 = [64,96)
    u16* hmlp    = (u16*)(base + 96 * MB);       // [M,1024] bf16 = [96,160)
    u16* outwt   = (u16*)(base + 96 * MB);       // [256][512] (written late)
    u16* fpw1t   = (u16*)obase;
    u16* fpw2t   = (u16*)(obase + 1 * MB);
    float* mag   = (float*)(obase + 2 * MB);
    float* cph   = mag + NB * NK;
    float* sph   = cph + NB * NK;
    float2* twid = (float2*)(obase + 4 * MB);
    u16* blkw1t  = (u16*)(obase + 6 * MB);       // 6 x [1024][512]
    u16* blkw2t  = (u16*)(obase + 12 * MB);      // 6 x [512][1024]

    // 0) twiddle table
    twiddle_kernel<<<8, 256, 0, stream>>>(twid);

    // 1) spectral embedding -> split bf16 feats
    dft_kernel<<<dim3(NB, NK), 256, 0, stream>>>(byte_ids, freq_bands, mag, cph, sph);
    feats_split_kernel<<<(NM * ND) / 256, 256, 0, stream>>>(mag, cph, sph, fhi, flo);
    wconv_kernel<<<dim3(NH / 32, ND / 32, 1), 256, 0, stream>>>(fp_w1, fpw1t, ND, NH);
    wconv_kernel<<<dim3(ND / 32, NH / 32, 1), 256, 0, stream>>>(fp_w2, fpw2t, NH, ND);
    wconv_kernel<<<dim3(NH / 32, ND / 32, NL), 256, 0, stream>>>(blk_w1, blkw1t, ND, NH);
    wconv_kernel<<<dim3(ND / 32, NH / 32, NL), 256, 0, stream>>>(blk_w2, blkw2t, NH, ND);

    // 2) freq_proj via fused split-bf16 MFMA (128-tile, 3-buffer pipeline)
    mfma_gemm2<<<dim3(NM / 128, NH / 128), 256, 0, stream>>>(
        fhi, flo, ND, fpw1t, fp_b1, hfp, ND, NH);
    ln_kernel<NH, 1, 2><<<NM, 256, 0, stream>>>(hfp, fp_ln_g, fp_ln_b, h2);
    mfma_gemm2<<<dim3(NM / 128, ND / 128), 256, 0, stream>>>(
        h2, h2 + NH, 2 * NH, fpw2t, fp_b2, xA, NH, ND);

    // 3) spectral MLP blocks: transpose-free mixing + MLP bf16 MFMA (256-tile)
    for (int l = 0; l < NL; ++l) {
        ln_fftd_kernel<<<NM / 4, 256, 0, stream>>>(
            xA, blk_ln1_g + l * ND, blk_ln1_b + l * ND, Pbuf, twid);
        fftt_direct_kernel<<<4112, 256, 0, stream>>>(Pbuf, Mtbuf, twid);
        addt_ln_kernel<<<dim3(NT / 16, NB), 256, 0, stream>>>(
            Mtbuf, xA, blk_ln2_g + l * ND, blk_ln2_b + l * ND, ybf);
        mfma_gemm<1, 0, 1, 1><<<dim3(NM / 256, NH / 128), 512, 0, stream>>>(
            ybf, ND, blkw1t + (size_t)l * ND * NH, blk_b1 + l * NH, hmlp, ND, NH);
        mfma_gemm<0, 1, 0, 1><<<dim3(NM / 256, ND / 128), 512, 0, stream>>>(
            hmlp, NH, blkw2t + (size_t)l * ND * NH, blk_b2 + l * ND, xA, NH, ND);
    }

    // 4) final norm + head (outwt into dead hmlp slot, disjoint from ybf)
    ln_kernel<ND, 0, 1><<<NM, 256, 0, stream>>>(xA, norm_g, norm_b, ybf);
    wconv_kernel<<<dim3(256 / 32, ND / 32, 1), 256, 0, stream>>>(out_w, outwt, ND, 256);
    mfma_gemm<0, 0, 0, 1><<<dim3(NM / 256, 256 / 128), 512, 0, stream>>>(
        ybf, ND, outwt, out_b, out, ND, 256);
}

// Round 22
// 2661.364 us; speedup vs baseline: 1.0530x; 1.0187x over previous
//
#include <hip/hip_runtime.h>
#include <cmath>

typedef unsigned short u16;
typedef unsigned int u32;

// Problem constants
constexpr int NB = 16;            // batch
constexpr int NT = 2048;          // seq len
constexpr int ND = 512;           // embed dim
constexpr int NL = 6;             // layers
constexpr int NH = 1024;          // mlp hidden
constexpr int NK = 256;           // freq bands kept
constexpr int NM = NB * NT;       // 32768 rows

constexpr float PI2 = 6.283185307179586f;

typedef short bf16x8 __attribute__((ext_vector_type(8)));
typedef float f32x4 __attribute__((ext_vector_type(4)));

__device__ __forceinline__ float gelu_exact(float v) {
    return 0.5f * v * (1.0f + erff(v * 0.70710678118654752f));
}

__device__ __forceinline__ u16 f2bf(float f) {
    union { float f; u32 u; } v; v.f = f;
    u32 r = v.u + 0x7FFFu + ((v.u >> 16) & 1u);
    return (u16)(r >> 16);
}

__device__ __forceinline__ float bf2f(u16 h) {
    union { u32 u; float f; } v; v.u = ((u32)h) << 16;
    return v.f;
}

__device__ __forceinline__ float block_sum256(float val, float* lds4) {
#pragma unroll
    for (int o = 32; o > 0; o >>= 1) val += __shfl_down(val, o);
    int lane = threadIdx.x & 63, wid = threadIdx.x >> 6;
    if (lane == 0) lds4[wid] = val;
    __syncthreads();
    float t = lds4[0] + lds4[1] + lds4[2] + lds4[3];
    __syncthreads();
    return t;
}

// XCD-chunked block swizzle (R12-proven). Tile size passed in.
__device__ __forceinline__ void swz_block_t(int bm, int& row0, int& col0) {
    int nwg = gridDim.x * gridDim.y;
    int wg = blockIdx.x + blockIdx.y * gridDim.x;
    int L = wg;
    if ((nwg & 7) == 0) {
        int q = nwg >> 3;
        L = (wg & 7) * q + (wg >> 3);
    }
    int ncol = gridDim.y;
    row0 = (L / ncol) * bm;
    col0 = (L % ncol) * 128;
}

// ---------------- twiddle table: entry (h-1)+k = exp(-i*pi*k/h) --------------
__global__ void twiddle_kernel(float2* __restrict__ tw) {
    int idx = blockIdx.x * 256 + threadIdx.x;
    if (idx < 2047) {
        u32 v = idx + 1;
        u32 h = 1u << (31 - __clz(v));
        u32 k = v - h;
        float a = -(float)M_PI * (float)k / (float)h;
        tw[idx] = make_float2(cosf(a), sinf(a));
    }
}

// ---------------- K1: direct DFT of byte signal, 16x256 bins -----------------
__global__ void dft_kernel(const int* __restrict__ bytes, const float* __restrict__ fb,
                           float* __restrict__ mag, float* __restrict__ cph,
                           float* __restrict__ sph) {
    __shared__ float lr[4], li[4];
    int b = blockIdx.x, f = blockIdx.y;
    float re = 0.f, im = 0.f;
    for (int t = threadIdx.x; t < NT; t += 256) {
        float s = (float)bytes[b * NT + t] * (1.0f / 127.5f) - 1.0f;
        int idx = (t * f) & (NT - 1);
        float a = (float)idx * (PI2 / NT);
        float sn, cs;
        sincosf(a, &sn, &cs);
        re += s * cs;
        im -= s * sn;
    }
#pragma unroll
    for (int o = 32; o > 0; o >>= 1) {
        re += __shfl_down(re, o);
        im += __shfl_down(im, o);
    }
    int lane = threadIdx.x & 63, wid = threadIdx.x >> 6;
    if (lane == 0) { lr[wid] = re; li[wid] = im; }
    __syncthreads();
    if (threadIdx.x == 0) {
        float R = lr[0] + lr[1] + lr[2] + lr[3];
        float I = li[0] + li[1] + li[2] + li[3];
        float m = sqrtf(R * R + I * I);
        mag[b * NK + f] = m * fb[f];
        float inv = (m > 0.f) ? 1.0f / m : 0.f;
        cph[b * NK + f] = (m > 0.f) ? R * inv : 1.0f;  // cos(angle)
        sph[b * NK + f] = I * inv;                     // sin(angle)
    }
}

// -------- K2: spectral features [mag | sin(phase)] -> split bf16 hi/lo -------
__global__ void feats_split_kernel(const float* __restrict__ mag,
                                   const float* __restrict__ cph,
                                   const float* __restrict__ sph,
                                   u16* __restrict__ hi, u16* __restrict__ lo) {
    int idx = blockIdx.x * 256 + threadIdx.x;
    int d = idx & (ND - 1);
    int m = idx >> 9;
    int b = m >> 11, t = m & (NT - 1);
    float v;
    if (d < NK) {
        v = mag[b * NK + d];
    } else {
        int f = d - NK;
        int a = (t * f) & (NT - 1);
        float sn, cs;
        sincosf((float)a * (PI2 / NT), &sn, &cs);
        v = sph[b * NK + f] * cs + cph[b * NK + f] * sn;  // sin(bp + theta)
    }
    u16 h = f2bf(v);
    hi[idx] = h;
    lo[idx] = f2bf(v - bf2f(h));
}

// ------- LayerNorm: OBF 0=f32 out, 1=bf16 out, 2=split hi/lo pair out --------
template <int NV, int GELU, int OBF>
__global__ void ln_kernel(const float* __restrict__ in, const float* __restrict__ g,
                          const float* __restrict__ bta, void* __restrict__ outv) {
    __shared__ float lds4[4];
    constexpr int NE = NV / 256;
    size_t row = blockIdx.x;
    const float* p = in + row * NV;
    float v[NE];
    float sum = 0.f;
#pragma unroll
    for (int i = 0; i < NE; ++i) {
        v[i] = p[threadIdx.x + 256 * i];
        sum += v[i];
    }
    sum = block_sum256(sum, lds4);
    float mean = sum * (1.0f / NV);
    float sq = 0.f;
#pragma unroll
    for (int i = 0; i < NE; ++i) {
        float d = v[i] - mean;
        sq += d * d;
    }
    sq = block_sum256(sq, lds4);
    float inv = rsqrtf(sq * (1.0f / NV) + 1e-5f);
#pragma unroll
    for (int i = 0; i < NE; ++i) {
        int c = threadIdx.x + 256 * i;
        float r = (v[i] - mean) * inv * g[c] + bta[c];
        if (GELU) r = gelu_exact(r);
        if (OBF == 2) {
            u16* o = (u16*)outv + row * (2 * NV);
            u16 hb = f2bf(r);
            o[c] = hb;
            o[NV + c] = f2bf(r - bf2f(hb));
        } else if (OBF == 1) {
            ((u16*)outv)[row * NV + c] = f2bf(r);
        } else {
            ((float*)outv)[row * NV + c] = r;
        }
    }
}

// ------- fused LN + 512-pt FFT along D, WAVE-PER-ROW (4 rows/block) ----------
__global__ void ln_fftd_kernel(const float* __restrict__ x, const float* __restrict__ g,
                               const float* __restrict__ bta, float* __restrict__ P,
                               const float2* __restrict__ twid) {
    __shared__ float sr[4][512], si[4][512];  // 16 KiB
    int wv = threadIdx.x >> 6, lane = threadIdx.x & 63;
    int rlocal = blockIdx.x * 4 + wv;
    const float* p = x + (size_t)rlocal * ND;
    float v[8];
    float s = 0.f;
#pragma unroll
    for (int j = 0; j < 8; ++j) { v[j] = p[lane + 64 * j]; s += v[j]; }
#pragma unroll
    for (int o = 32; o > 0; o >>= 1) s += __shfl_down(s, o);
    s = __shfl(s, 0);
    float mean = s * (1.0f / ND);
    float q = 0.f;
#pragma unroll
    for (int j = 0; j < 8; ++j) { float d = v[j] - mean; q += d * d; }
#pragma unroll
    for (int o = 32; o > 0; o >>= 1) q += __shfl_down(q, o);
    q = __shfl(q, 0);
    float inv = rsqrtf(q * (1.0f / ND) + 1e-5f);
#pragma unroll
    for (int j = 0; j < 8; ++j) {
        int i = lane + 64 * j;
        int r = __brev((unsigned)i) >> 23;  // 9-bit reverse
        sr[wv][r] = (v[j] - mean) * inv * g[i] + bta[i];
        si[wv][r] = 0.f;
    }
    for (int len = 2; len <= 512; len <<= 1) {
        int half = len >> 1;
#pragma unroll
        for (int qq = lane; qq < 256; qq += 64) {
            int k = qq & (half - 1);
            int j = ((qq - k) << 1) + k;
            float2 tw = twid[(half - 1) + k];
            float cs = tw.x, sn = tw.y;
            float ur = sr[wv][j], ui = si[wv][j];
            float vr = sr[wv][j + half], vi = si[wv][j + half];
            float tr = vr * cs - vi * sn;
            float ti = vr * sn + vi * cs;
            sr[wv][j] = ur + tr;
            si[wv][j] = ui + ti;
            sr[wv][j + half] = ur - tr;
            si[wv][j + half] = ui - ti;
        }
    }
    float* out = P + (size_t)rlocal * ND;
#pragma unroll
    for (int j = 0; j < 8; ++j) {
        int i = lane + 64 * j;
        out[i] = (i <= 256) ? sr[wv][i] : si[wv][i - 256];
    }
}

// ---- FFT along T reading P directly; TWO d-columns per block (float2) -------
// XCD d-chunk remap (R12/R21-proven): XCD x owns d in [32x,32x+32).
// Pair (d0, d0+1), d0 even -> 8B-aligned float2 gathers (half the loads).
__global__ void fftt_direct_kernel(const float* __restrict__ P, float* __restrict__ Mt,
                                   const float2* __restrict__ twid) {
    __shared__ float sr[2][2048], si[2][2048];  // 32 KiB
    int wg = blockIdx.x;
    int x = wg & 7, p = wg >> 3;
    int b, d0;
    bool pair;
    if (p < 256) { d0 = x * 32 + 2 * (p & 15); b = p >> 4; pair = true; }
    else         { d0 = 256; b = x * 2 + (p - 256); pair = false; }
    const float* pr = P + (size_t)b * NT * ND + d0;
    const float* pi = P + (size_t)b * NT * ND + 256 + d0;
    if (pair) {
        for (int t = threadIdx.x; t < 2048; t += 256) {
            int r = __brev((unsigned)t) >> 21;  // 11-bit reverse
            float2 vr = *(const float2*)&pr[(size_t)t * ND];
            float2 vi = *(const float2*)&pi[(size_t)t * ND];
            sr[0][r] = vr.x; sr[1][r] = vr.y;
            si[0][r] = (d0 != 0) ? vi.x : 0.f;
            si[1][r] = vi.y;
        }
    } else {
        for (int t = threadIdx.x; t < 2048; t += 256) {
            int r = __brev((unsigned)t) >> 21;
            sr[0][r] = pr[(size_t)t * ND];
            si[0][r] = 0.f;
        }
    }
    __syncthreads();
    int nwork = pair ? 2048 : 1024;
    for (int len = 2; len <= 2048; len <<= 1) {
        int half = len >> 1;
        for (int q = threadIdx.x; q < nwork; q += 256) {
            int c = q >> 10;
            int i = q & 1023;
            int k = i & (half - 1);
            int j = ((i - k) << 1) + k;
            float2 tw = twid[(half - 1) + k];
            float cs = tw.x, sn = tw.y;
            float ur = sr[c][j], ui = si[c][j];
            float vr = sr[c][j + half], vi = si[c][j + half];
            float tr = vr * cs - vi * sn;
            float ti = vr * sn + vi * cs;
            sr[c][j] = ur + tr;
            si[c][j] = ui + ti;
            sr[c][j + half] = ur - tr;
            si[c][j + half] = ui - ti;
        }
        __syncthreads();
    }
    int ncol = pair ? 2 : 1;
    for (int c = 0; c < ncol; ++c) {
        int d = d0 + c;
        float* m0 = Mt + ((size_t)(b * ND + d)) * NT;
        for (int t = threadIdx.x; t < 2048; t += 256) m0[t] = sr[c][t];
        if (d != 0 && d != 256) {
            float* m1 = Mt + ((size_t)(b * ND + (512 - d))) * NT;
            for (int t = threadIdx.x; t < 2048; t += 256) m1[t] = sr[c][(2048 - t) & 2047];
        }
    }
}

// ------- FUSED: x[b,t,d] += Mt[b,d,t]; then LN2 -> ybf (bf16) ---------------
__global__ void addt_ln_kernel(const float* __restrict__ Mt, float* __restrict__ x,
                               const float* __restrict__ g, const float* __restrict__ bta,
                               u16* __restrict__ yb) {
    __shared__ float tile[512 * 17];  // [d][tloc] stride 17 (34.8KB, 2-way banks)
    int b = blockIdx.y, t0 = blockIdx.x * 16;
    int tid = threadIdx.x;
    for (int lin = tid; lin < 512 * 16; lin += 256) {
        int tloc = lin & 15, d = lin >> 4;
        tile[d * 17 + tloc] = Mt[((size_t)(b * ND + d)) * NT + t0 + tloc];
    }
    __syncthreads();
    int lane = tid & 63, wv = tid >> 6;
#pragma unroll
    for (int rr = 0; rr < 4; ++rr) {
        int tloc = wv * 4 + rr;
        size_t row = (size_t)(b * NT + t0 + tloc);
        float v[8];
        float s = 0.f;
#pragma unroll
        for (int e = 0; e < 8; ++e) {
            int d = lane + 64 * e;
            v[e] = x[row * ND + d] + tile[d * 17 + tloc];
            s += v[e];
        }
#pragma unroll
        for (int o = 32; o > 0; o >>= 1) s += __shfl_down(s, o);
        s = __shfl(s, 0);
        float mean = s * (1.0f / ND);
        float q = 0.f;
#pragma unroll
        for (int e = 0; e < 8; ++e) { float d2 = v[e] - mean; q += d2 * d2; }
#pragma unroll
        for (int o = 32; o > 0; o >>= 1) q += __shfl_down(q, o);
        q = __shfl(q, 0);
        float inv = rsqrtf(q * (1.0f / ND) + 1e-5f);
#pragma unroll
        for (int e = 0; e < 8; ++e) {
            int d = lane + 64 * e;
            x[row * ND + d] = v[e];
            yb[row * ND + d] = f2bf((v[e] - mean) * inv * g[d] + bta[d]);
        }
    }
}

// ---------------- weight transpose + f32->bf16: Wt[n][k] = W[k][n] -----------
__global__ void wconv_kernel(const float* __restrict__ W, u16* __restrict__ Wt,
                             int K, int N) {
    __shared__ float tile[32][33];
    size_t moff = (size_t)blockIdx.z * K * N;
    int n0 = blockIdx.x * 32, k0 = blockIdx.y * 32;
    int j = threadIdx.x & 31, i0 = threadIdx.x >> 5;
    for (int i = i0; i < 32; i += 8)
        tile[i][j] = W[moff + (size_t)(k0 + i) * N + n0 + j];
    __syncthreads();
    for (int i = i0; i < 32; i += 8)
        Wt[moff + (size_t)(n0 + i) * K + k0 + j] = f2bf(tile[j][i]);
}

// ------- bf16 MFMA GEMM: 256x128 tile, 8 waves, 2-buffer gload_lds -----------
template <int GELU, int ACC, int OBF, int ADDB>
__global__ __launch_bounds__(512) void mfma_gemm(
    const u16* __restrict__ A, int lda, const u16* __restrict__ Wt,
    const float* __restrict__ bias, void* __restrict__ Cv, int Kd, int Nd) {
    __shared__ __align__(16) u16 Al[2][8192];
    __shared__ __align__(16) u16 Bl[2][4096];
    int tid = threadIdx.x;
    int row0, col0;
    swz_block_t(256, row0, col0);
    int lane = tid & 63, w = tid >> 6;
    int wr = w >> 1, wc = w & 1;      // wr 0..3, wc 0..1
    int kg = lane >> 4, ln16 = lane & 15;

    f32x4 acc[4][4] = {};

    auto stage = [&](int buf, int t) {
        int k0 = t << 5;
#pragma unroll
        for (int i = 0; i < 2; ++i) {   // A: 1024 slots, 512 threads
            int s = i * 512 + tid;
            int skg = s >> 8, r = s & 255;
            const u16* ga = A + (size_t)(row0 + r) * lda + k0 + skg * 8;
            __builtin_amdgcn_global_load_lds(
                (const __attribute__((address_space(1))) void*)ga,
                (__attribute__((address_space(3))) void*)&Al[buf][s * 8], 16, 0, 0);
        }
        {                               // B: 512 slots
            int s = tid;
            int skg = s >> 7, r = s & 127;
            const u16* gb = Wt + (size_t)(col0 + r) * Kd + k0 + skg * 8;
            __builtin_amdgcn_global_load_lds(
                (const __attribute__((address_space(1))) void*)gb,
                (__attribute__((address_space(3))) void*)&Bl[buf][s * 8], 16, 0, 0);
        }
    };
    auto compute = [&](int buf) {
        bf16x8 af[4], bfr[4];
#pragma unroll
        for (int mi = 0; mi < 4; ++mi)
            af[mi] = *(const bf16x8*)&Al[buf][(kg * 256 + wr * 64 + mi * 16 + ln16) * 8];
#pragma unroll
        for (int ni = 0; ni < 4; ++ni)
            bfr[ni] = *(const bf16x8*)&Bl[buf][(kg * 128 + wc * 64 + ni * 16 + ln16) * 8];
#pragma unroll
        for (int mi = 0; mi < 4; ++mi)
#pragma unroll
            for (int ni = 0; ni < 4; ++ni)
                acc[mi][ni] = __builtin_amdgcn_mfma_f32_16x16x32_bf16(
                    af[mi], bfr[ni], acc[mi][ni], 0, 0, 0);
    };

    int nt = Kd >> 5;
    stage(0, 0);
    __syncthreads();
    int cur = 0;
    for (int t = 1; t < nt; ++t) {
        stage(cur ^ 1, t);
        compute(cur);
        __syncthreads();
        cur ^= 1;
    }
    compute(cur);

#pragma unroll
    for (int mi = 0; mi < 4; ++mi) {
#pragma unroll
        for (int ni = 0; ni < 4; ++ni) {
            int col = col0 + wc * 64 + ni * 16 + ln16;
            float bv = ADDB ? bias[col] : 0.f;
#pragma unroll
            for (int j = 0; j < 4; ++j) {
                int row = row0 + wr * 64 + mi * 16 + kg * 4 + j;
                float v = acc[mi][ni][j] + bv;
                if (GELU) v = gelu_exact(v);
                size_t o = (size_t)row * Nd + col;
                if (OBF) {
                    ((u16*)Cv)[o] = f2bf(v);
                } else {
                    float* C = (float*)Cv;
                    if (ACC) v += C[o];
                    C[o] = v;
                }
            }
        }
    }
}

// ------- fused split-bf16 GEMM: 128x128, 3-buffer counted-vmcnt (R12) --------
__global__ __launch_bounds__(256) void mfma_gemm2(
    const u16* __restrict__ Ahi, const u16* __restrict__ Alo, int lda,
    const u16* __restrict__ Wt, const float* __restrict__ bias,
    float* __restrict__ C, int Kd, int Nd) {
    __shared__ __align__(16) u16 Ah[3][4096];
    __shared__ __align__(16) u16 Al2[3][4096];
    __shared__ __align__(16) u16 Bl[3][4096];
    int tid = threadIdx.x;
    int row0, col0;
    swz_block_t(128, row0, col0);
    int lane = tid & 63, w = tid >> 6;
    int wr = w >> 1, wc = w & 1;
    int kg = lane >> 4, ln16 = lane & 15;

    f32x4 acc[4][4] = {};

    auto stage = [&](int buf, int t) {
        int k0 = t << 5;
#pragma unroll
        for (int i = 0; i < 2; ++i) {
            int s = i * 256 + tid;
            int skg = s >> 7, r = s & 127;
            size_t aoff = (size_t)(row0 + r) * lda + k0 + skg * 8;
            __builtin_amdgcn_global_load_lds(
                (const __attribute__((address_space(1))) void*)(Ahi + aoff),
                (__attribute__((address_space(3))) void*)&Ah[buf][s * 8], 16, 0, 0);
            __builtin_amdgcn_global_load_lds(
                (const __attribute__((address_space(1))) void*)(Alo + aoff),
                (__attribute__((address_space(3))) void*)&Al2[buf][s * 8], 16, 0, 0);
            const u16* gb = Wt + (size_t)(col0 + r) * Kd + k0 + skg * 8;
            __builtin_amdgcn_global_load_lds(
                (const __attribute__((address_space(1))) void*)gb,
                (__attribute__((address_space(3))) void*)&Bl[buf][s * 8], 16, 0, 0);
        }
    };
    auto compute = [&](int buf) {
        bf16x8 ah[4], al[4], bfr[4];
#pragma unroll
        for (int mi = 0; mi < 4; ++mi) {
            int sl = (kg * 128 + wr * 64 + mi * 16 + ln16) * 8;
            ah[mi] = *(const bf16x8*)&Ah[buf][sl];
            al[mi] = *(const bf16x8*)&Al2[buf][sl];
        }
#pragma unroll
        for (int ni = 0; ni < 4; ++ni)
            bfr[ni] = *(const bf16x8*)&Bl[buf][(kg * 128 + wc * 64 + ni * 16 + ln16) * 8];
#pragma unroll
        for (int mi = 0; mi < 4; ++mi)
#pragma unroll
            for (int ni = 0; ni < 4; ++ni) {
                acc[mi][ni] = __builtin_amdgcn_mfma_f32_16x16x32_bf16(
                    ah[mi], bfr[ni], acc[mi][ni], 0, 0, 0);
                acc[mi][ni] = __builtin_amdgcn_mfma_f32_16x16x32_bf16(
                    al[mi], bfr[ni], acc[mi][ni], 0, 0, 0);
            }
    };

    int nt = Kd >> 5;
    stage(0, 0);
    stage(1, 1);
    for (int t = 0; t < nt; ++t) {
        if (t + 1 < nt) asm volatile("s_waitcnt vmcnt(6)" ::: "memory");
        else            asm volatile("s_waitcnt vmcnt(0)" ::: "memory");
        __builtin_amdgcn_sched_barrier(0);
        __builtin_amdgcn_s_barrier();
        __builtin_amdgcn_sched_barrier(0);
        if (t + 2 < nt) stage((t + 2) % 3, t + 2);
        compute(t % 3);
    }

#pragma unroll
    for (int mi = 0; mi < 4; ++mi) {
#pragma unroll
        for (int ni = 0; ni < 4; ++ni) {
            int col = col0 + wc * 64 + ni * 16 + ln16;
            float bv = bias[col];
#pragma unroll
            for (int j = 0; j < 4; ++j) {
                int row = row0 + wr * 64 + mi * 16 + kg * 4 + j;
                C[(size_t)row * Nd + col] = acc[mi][ni][j] + bv;
            }
        }
    }
}

extern "C" void kernel_launch(void* const* d_in, const int* in_sizes, int n_in,
                              void* d_out, int out_size, void* d_ws, size_t ws_size,
                              hipStream_t stream) {
    const int* byte_ids     = (const int*)d_in[0];
    const float* freq_bands = (const float*)d_in[1];
    const float* fp_w1   = (const float*)d_in[2];
    const float* fp_b1   = (const float*)d_in[3];
    const float* fp_ln_g = (const float*)d_in[4];
    const float* fp_ln_b = (const float*)d_in[5];
    const float* fp_w2   = (const float*)d_in[6];
    const float* fp_b2   = (const float*)d_in[7];
    const float* blk_ln1_g = (const float*)d_in[8];
    const float* blk_ln1_b = (const float*)d_in[9];
    const float* blk_ln2_g = (const float*)d_in[10];
    const float* blk_ln2_b = (const float*)d_in[11];
    const float* blk_w1  = (const float*)d_in[12];
    const float* blk_b1  = (const float*)d_in[13];
    const float* blk_w2  = (const float*)d_in[14];
    const float* blk_b2  = (const float*)d_in[15];
    const float* norm_g  = (const float*)d_in[16];
    const float* norm_b  = (const float*)d_in[17];
    const float* out_w   = (const float*)d_in[18];
    const float* out_b   = (const float*)d_in[19];
    float* out = (float*)d_out;
    char* base = (char*)d_ws;
    char* obase = (char*)d_out;
    const size_t MB = 1048576;

    // ---- Workspace map (192 MiB), R21 slotting (transpose-free mixing):
    u16* fhi     = (u16*)base;
    u16* flo     = (u16*)(base + 32 * MB);
    float* xA    = (float*)base;                 // [M,512] f32 = [0,64)
    float* hfp   = (float*)(base + 64 * MB);     // [M,1024] f32 = [64,192)
    u16* h2      = (u16*)hfp;
    float* Pbuf  = (float*)(base + 64 * MB);     // [M,512] f32 = [64,128)
    float* Mtbuf = (float*)(base + 128 * MB);    // [B,512,2048] f32 = [128,192)
    u16* ybf     = (u16*)(base + 64 * MB);       // [M,512] bf16 = [64,96)
    u16* hmlp    = (u16*)(base + 96 * MB);       // [M,1024] bf16 = [96,160)
    u16* outwt   = (u16*)(base + 96 * MB);       // [256][512] (written late)
    u16* fpw1t   = (u16*)obase;
    u16* fpw2t   = (u16*)(obase + 1 * MB);
    float* mag   = (float*)(obase + 2 * MB);
    float* cph   = mag + NB * NK;
    float* sph   = cph + NB * NK;
    float2* twid = (float2*)(obase + 4 * MB);
    u16* blkw1t  = (u16*)(obase + 6 * MB);       // 6 x [1024][512]
    u16* blkw2t  = (u16*)(obase + 12 * MB);      // 6 x [512][1024]

    // 0) twiddle table
    twiddle_kernel<<<8, 256, 0, stream>>>(twid);

    // 1) spectral embedding -> split bf16 feats
    dft_kernel<<<dim3(NB, NK), 256, 0, stream>>>(byte_ids, freq_bands, mag, cph, sph);
    feats_split_kernel<<<(NM * ND) / 256, 256, 0, stream>>>(mag, cph, sph, fhi, flo);
    wconv_kernel<<<dim3(NH / 32, ND / 32, 1), 256, 0, stream>>>(fp_w1, fpw1t, ND, NH);
    wconv_kernel<<<dim3(ND / 32, NH / 32, 1), 256, 0, stream>>>(fp_w2, fpw2t, NH, ND);
    wconv_kernel<<<dim3(NH / 32, ND / 32, NL), 256, 0, stream>>>(blk_w1, blkw1t, ND, NH);
    wconv_kernel<<<dim3(ND / 32, NH / 32, NL), 256, 0, stream>>>(blk_w2, blkw2t, NH, ND);

    // 2) freq_proj via fused split-bf16 MFMA (128-tile, 3-buffer pipeline)
    mfma_gemm2<<<dim3(NM / 128, NH / 128), 256, 0, stream>>>(
        fhi, flo, ND, fpw1t, fp_b1, hfp, ND, NH);
    ln_kernel<NH, 1, 2><<<NM, 256, 0, stream>>>(hfp, fp_ln_g, fp_ln_b, h2);
    mfma_gemm2<<<dim3(NM / 128, ND / 128), 256, 0, stream>>>(
        h2, h2 + NH, 2 * NH, fpw2t, fp_b2, xA, NH, ND);

    // 3) spectral MLP blocks: transpose-free mixing (paired cols) + MLP MFMA
    for (int l = 0; l < NL; ++l) {
        ln_fftd_kernel<<<NM / 4, 256, 0, stream>>>(
            xA, blk_ln1_g + l * ND, blk_ln1_b + l * ND, Pbuf, twid);
        fftt_direct_kernel<<<2064, 256, 0, stream>>>(Pbuf, Mtbuf, twid);
        addt_ln_kernel<<<dim3(NT / 16, NB), 256, 0, stream>>>(
            Mtbuf, xA, blk_ln2_g + l * ND, blk_ln2_b + l * ND, ybf);
        mfma_gemm<1, 0, 1, 1><<<dim3(NM / 256, NH / 128), 512, 0, stream>>>(
            ybf, ND, blkw1t + (size_t)l * ND * NH, blk_b1 + l * NH, hmlp, ND, NH);
        mfma_gemm<0, 1, 0, 1><<<dim3(NM / 256, ND / 128), 512, 0, stream>>>(
            hmlp, NH, blkw2t + (size_t)l * ND * NH, blk_b2 + l * ND, xA, NH, ND);
    }

    // 4) final norm + head (outwt into dead hmlp slot, disjoint from ybf)
    ln_kernel<ND, 0, 1><<<NM, 256, 0, stream>>>(xA, norm_g, norm_b, ybf);
    wconv_kernel<<<dim3(256 / 32, ND / 32, 1), 256, 0, stream>>>(out_w, outwt, ND, 256);
    mfma_gemm<0, 0, 0, 1><<<dim3(NM / 256, 256 / 128), 512, 0, stream>>>(
        ybf, ND, outwt, out_b, out, ND, 256);
}